// Round 10
// baseline (811.241 us; speedup 1.0000x reference)
//
#include <hip/hip_runtime.h>
#include <cstdint>

#define B_    8
#define T_    16384
#define NA_   512
#define A_    512
#define NIT_  32
#define EPSV  1e-8f

typedef unsigned long long u64;
typedef __attribute__((ext_vector_type(8))) short bf16x8;
typedef __attribute__((ext_vector_type(4))) float f32x4;

union Frag { uint4 u; bf16x8 f; };

// ws float-offset layout
#define OFF_INV   0
#define OFF_SELA  512
#define OFF_SELT  768
#define OFF_SELV  1024
#define OFF_CM    1280        // u64[8*512*256] (fallback path only)
#define OFF_RMA   2098432     // persistent: rmW u64[2][256]; fallback: rm u64[4096]
#define OFF_RMB   2106624     // u64[4096] (fallback)
#define OFF_XRA   2114816     // f32[8*16384]
#define OFF_XRB   2245888     // f32[8*16384]
#define OFF_DPK   2376960     // u32[512*512]  (fallback path only)
#define MAIN_NEED 2639104     // launch-loop requirement
#define OFF_BAR   2639104     // u32 gen-slots: 8 batches x 32 blocks x 16-dword stride
#define PERS_NEED (OFF_BAR + 4096)
// compact fallback layout
#define OFF_SXR   OFF_CM
#define OFF_SCAND (OFF_CM + 131072)
#define S_NEED    (OFF_SCAND + 16)

__device__ __forceinline__ unsigned int encf(float f) {
    unsigned int u = __float_as_uint(f);
    return (u & 0x80000000u) ? ~u : (u | 0x80000000u);
}
__device__ __forceinline__ float decf(unsigned int e) {
    unsigned int u = (e & 0x80000000u) ? (e & 0x7fffffffu) : ~e;
    return __uint_as_float(u);
}
__device__ __forceinline__ u64 umax64(u64 a, u64 b) { return a > b ? a : b; }
__device__ __forceinline__ u64 enc64(float v, unsigned int flat) {
    return (((u64)encf(v)) << 32) | (unsigned int)~flat;
}
__device__ __forceinline__ u64 shfl_xor_u64(u64 v, int mask) {
    unsigned int lo = (unsigned int)v, hi = (unsigned int)(v >> 32);
    lo = __shfl_xor(lo, mask, 64);
    hi = __shfl_xor(hi, mask, 64);
    return (((u64)hi) << 32) | lo;
}
__device__ __forceinline__ u64 shfl_down_u64(u64 v, int off) {
    unsigned int lo = (unsigned int)v, hi = (unsigned int)(v >> 32);
    lo = __shfl_down(lo, off, 64);
    hi = __shfl_down(hi, off, 64);
    return (((u64)hi) << 32) | lo;
}
// bf16 round-to-nearest-even from fp32
__device__ __forceinline__ unsigned short f2bf(float v) {
    unsigned int u = __float_as_uint(v);
    return (unsigned short)((u + 0x7fffu + ((u >> 16) & 1u)) >> 16);
}
// float -> (hi-bf16 | lo-bf16<<16), bit-identical to k_split_d
__device__ __forceinline__ unsigned int packhl(float v) {
    unsigned short hb = f2bf(v);
    unsigned short lb = f2bf(v - __uint_as_float((unsigned int)hb << 16));
    return (unsigned int)hb | ((unsigned int)lb << 16);
}

// agent-scope (cross-XCD coherent, L2-bypassing) data ops (r5-proven).
__device__ __forceinline__ float ld_af(const float* p) {
    return __hip_atomic_load(p, __ATOMIC_RELAXED, __HIP_MEMORY_SCOPE_AGENT);
}
__device__ __forceinline__ void st_af(float* p, float v) {
    __hip_atomic_store(p, v, __ATOMIC_RELAXED, __HIP_MEMORY_SCOPE_AGENT);
}
__device__ __forceinline__ u64 ld_au64(const u64* p) {
    return __hip_atomic_load(p, __ATOMIC_RELAXED, __HIP_MEMORY_SCOPE_AGENT);
}
__device__ __forceinline__ void st_au64(u64* p, u64 v) {
    __hip_atomic_store(p, v, __ATOMIC_RELAXED, __HIP_MEMORY_SCOPE_AGENT);
}

// per-b 32-block distributed-flag barrier (r10). Replaces r5's contended
// atomicAdd counter (32 serialized RMWs on one line at the coherence point,
// ~2.7-5 us/iter) with: each block STORES its generation stamp to its own
// 64B-spaced slot (parallel, no RMW); wave 0's lanes poll the 32 slots in
// parallel (lane polls slot[lane&31]; wave reconverges when all lanes see
// >= gen). Ordering identical to r5-proven scheme: the leading __syncthreads
// drains every wave's vmcnt -> all agent data stores (incl. tid0's own rmW
// winner store) are globally visible before tid0's arrival store issues.
// Bounded spin = degrade, never hang.
__device__ __forceinline__ void b_barrier(unsigned int* slots, int ag, unsigned int gen) {
    __syncthreads();
    const int tid = threadIdx.x;
    if (tid == 0)
        __hip_atomic_store(&slots[ag << 4], gen, __ATOMIC_RELAXED, __HIP_MEMORY_SCOPE_AGENT);
    if (tid < 64) {
        const unsigned int* sp = &slots[(tid & 31) << 4];
        int spins = 0;
        while (__hip_atomic_load(sp, __ATOMIC_RELAXED, __HIP_MEMORY_SCOPE_AGENT) < gen) {
            __builtin_amdgcn_s_sleep(1);
            if (++spins > (1 << 20)) break;   // safety valve
        }
    }
    __syncthreads();
    asm volatile("" ::: "memory");
}

// one 128-t super-chunk (chunks c0, c0+1): 8 output t-tiles x 32 K-steps,
// 8-deep rotating B-fragment file (Toeplitz slide), A-fragments from swizzled
// LDS (dl4). REFILLS MUST RUN FOR ALL js (r7 lesson): the refill at step js
// loads F(js+8), consumed at steps js+1..js+7 by higher tiles. With callers
// keeping c0 <= 15, max read index = 16*15 + 4*39 = 396 < 410 (in-range).
// Accumulation order per tile: bh(js) then bl(js), js ascending -- identical
// to the original k_conv/k_it order.
__device__ __forceinline__ void run_super(const uint4* bhp, const uint4* blp,
                                          const uint4* Adl, int sw,
                                          int c0, int tbase, int chbase,
                                          u64* cml, const float* ivv,
                                          int a0, int q, int cl) {
    const int base = c0 << 4;
    f32x4 acc[8];
    const f32x4 zero = {0.f, 0.f, 0.f, 0.f};
    #pragma unroll
    for (int g = 0; g < 8; ++g) acc[g] = zero;

    Frag bh[8], bl[8];
    #pragma unroll
    for (int pp = 0; pp < 8; ++pp) {
        bh[pp].u = bhp[base + 4 * pp];
        bl[pp].u = blp[base + 4 * pp];
    }
    for (int js0 = 0; js0 < 32; js0 += 8) {
        #pragma unroll
        for (int ju = 0; ju < 8; ++ju) {
            const int js = js0 + ju;
            Frag Af;
            Af.u = Adl[(q + 4 * js) ^ sw];
            #pragma unroll
            for (int g = 0; g < 8; ++g)
                acc[g] = __builtin_amdgcn_mfma_f32_16x16x32_bf16(Af.f, bh[(g + ju) & 7].f, acc[g], 0, 0, 0);
            #pragma unroll
            for (int g = 0; g < 8; ++g)
                acc[g] = __builtin_amdgcn_mfma_f32_16x16x32_bf16(Af.f, bl[(g + ju) & 7].f, acc[g], 0, 0, 0);
            bh[ju].u = bhp[base + 4 * (js + 8)];
            bl[ju].u = blp[base + 4 * (js + 8)];
        }
    }
    #pragma unroll
    for (int r = 0; r < 4; ++r) {
        const int atom4 = 4 * q + r;
        const int atom = a0 + atom4;
        u64 m0 = 0ull, m1 = 0ull;
        #pragma unroll
        for (int g = 0; g < 4; ++g) {
            int t = tbase + 64 * c0 + 16 * g + cl;
            m0 = umax64(m0, enc64(acc[g][r] * ivv[r], (unsigned int)(atom * T_ + t)));
        }
        #pragma unroll
        for (int g = 4; g < 8; ++g) {
            int t = tbase + 64 * c0 + 16 * g + cl;
            m1 = umax64(m1, enc64(acc[g][r] * ivv[r], (unsigned int)(atom * T_ + t)));
        }
        m0 = umax64(m0, shfl_xor_u64(m0, 1));
        m0 = umax64(m0, shfl_xor_u64(m0, 2));
        m0 = umax64(m0, shfl_xor_u64(m0, 4));
        m0 = umax64(m0, shfl_xor_u64(m0, 8));
        m1 = umax64(m1, shfl_xor_u64(m1, 1));
        m1 = umax64(m1, shfl_xor_u64(m1, 2));
        m1 = umax64(m1, shfl_xor_u64(m1, 4));
        m1 = umax64(m1, shfl_xor_u64(m1, 8));
        if (cl == 0) {
            cml[(atom4 << 8) + chbase + c0] = m0;
            cml[(atom4 << 8) + chbase + c0 + 1] = m1;
        }
    }
}

// one 64-t chunk: 4 output t-tiles, 4-deep rotation with FULL refills
// (r3-proven pattern). Max read index = 16*16 + 4*35 = 396 < 410.
__device__ __forceinline__ void run_single(const uint4* bhp, const uint4* blp,
                                           const uint4* Adl, int sw,
                                           int c, int tbase, int chbase,
                                           u64* cml, const float* ivv,
                                           int a0, int q, int cl) {
    const int base = c << 4;
    f32x4 acc[4];
    const f32x4 zero = {0.f, 0.f, 0.f, 0.f};
    #pragma unroll
    for (int g = 0; g < 4; ++g) acc[g] = zero;

    Frag bh[4], bl[4];
    #pragma unroll
    for (int pp = 0; pp < 4; ++pp) {
        bh[pp].u = bhp[base + 4 * pp];
        bl[pp].u = blp[base + 4 * pp];
    }
    for (int js0 = 0; js0 < 32; js0 += 4) {
        #pragma unroll
        for (int ju = 0; ju < 4; ++ju) {
            const int js = js0 + ju;
            Frag Af;
            Af.u = Adl[(q + 4 * js) ^ sw];
            #pragma unroll
            for (int g = 0; g < 4; ++g)
                acc[g] = __builtin_amdgcn_mfma_f32_16x16x32_bf16(Af.f, bh[(g + ju) & 3].f, acc[g], 0, 0, 0);
            #pragma unroll
            for (int g = 0; g < 4; ++g)
                acc[g] = __builtin_amdgcn_mfma_f32_16x16x32_bf16(Af.f, bl[(g + ju) & 3].f, acc[g], 0, 0, 0);
            bh[ju].u = bhp[base + 4 * (js + 4)];
            bl[ju].u = blp[base + 4 * (js + 4)];
        }
    }
    #pragma unroll
    for (int r = 0; r < 4; ++r) {
        const int atom4 = 4 * q + r;
        const int atom = a0 + atom4;
        u64 m0 = 0ull;
        #pragma unroll
        for (int g = 0; g < 4; ++g) {
            int t = tbase + 64 * c + 16 * g + cl;
            m0 = umax64(m0, enc64(acc[g][r] * ivv[r], (unsigned int)(atom * T_ + t)));
        }
        m0 = umax64(m0, shfl_xor_u64(m0, 1));
        m0 = umax64(m0, shfl_xor_u64(m0, 2));
        m0 = umax64(m0, shfl_xor_u64(m0, 4));
        m0 = umax64(m0, shfl_xor_u64(m0, 8));
        if (cl == 0)
            cml[(atom4 << 8) + chbase + c] = m0;
    }
}

// ---------------- inv[a] = 1/(||d_a||+eps); also zero barrier slots ----------------
__global__ __launch_bounds__(64) void k_inv(const float* __restrict__ d, float* __restrict__ inv,
                                            unsigned int* __restrict__ bar) {
    const int a = blockIdx.x, lane = threadIdx.x;
    if (bar && a == 0) {
        for (int i = lane; i < 4096; i += 64) bar[i] = 0u;
    }
    const float* row = d + a * A_;
    float s = 0.f;
    for (int i = lane; i < A_; i += 64) { float v = row[i]; s = fmaf(v, v, s); }
    #pragma unroll
    for (int o = 32; o > 0; o >>= 1) s += __shfl_down(s, o, 64);
    if (lane == 0) inv[a] = 1.0f / (sqrtf(s) + EPSV);
}

// ---------------- d -> packed (hi | lo<<16) (fallback path only) ----------------
__global__ __launch_bounds__(256) void k_split_d(const float* __restrict__ d,
                                                 unsigned int* __restrict__ dpk) {
    int id = blockIdx.x * 256 + threadIdx.x;           // 262144
    dpk[id] = packhl(d[id]);
}

// ---------------- persistent everything-kernel ----------------
// grid (32 ag, 8 b) = 256 blocks; ~116 KB LDS forces 1 block/CU, grid == CU
// count -> co-resident -> software barrier safe (r5-proven).
// r10: contended-RMW barrier replaced with distributed gen-stamp slots
// (store + parallel poll, no atomicAdd chain). Everything else == r9.
__global__ __launch_bounds__(512) void k_persist(const float* __restrict__ x,
                                                 float* __restrict__ xrA,
                                                 float* __restrict__ xrB,
                                                 const float* __restrict__ d,
                                                 const float* __restrict__ inv,
                                                 u64* __restrict__ rmW,
                                                 int* __restrict__ selA,
                                                 int* __restrict__ selT,
                                                 float* __restrict__ selV,
                                                 unsigned int* __restrict__ bar,
                                                 float* __restrict__ out) {
    __shared__ u64 red16[16];
    __shared__ int   selAL[NIT_];
    __shared__ int   selTL[NIT_];
    __shared__ float selVL[NIT_];
    __shared__ uint4 s_hh[4][410];
    __shared__ uint4 s_ll[4][410];
    __shared__ uint4 dl4[16 * 128];     // 32 KB swizzled packed-d rows a0..a0+15
    __shared__ u64  cml[16 * 256];      // 32 KB block-private cm rows
    const int ag = blockIdx.x, b = blockIdx.y, tid = threadIdx.x;
    const int wave = tid >> 6, lane = tid & 63;
    const int cl = lane & 15, q = lane >> 4;
    const int a0 = ag * 16;
    unsigned int* slots = bar + (b << 9);   // 32 slots x 16-dword stride

    // ---- one-time dpk staging: convert d in-kernel (packing == k_split_d),
    // swizzled dest (conflict-free b128 reads) ----
    {
        const float4* gsrc = (const float4*)(d + (a0 << 9));
        #pragma unroll
        for (int s = 0; s < 4; ++s) {
            int i = tid + 512 * s;
            int row = i >> 7, c4 = i & 127;
            float4 f = gsrc[i];
            uint4 pk;
            pk.x = packhl(f.x);
            pk.y = packhl(f.y);
            pk.z = packhl(f.z);
            pk.w = packhl(f.w);
            dl4[(row << 7) | (c4 ^ (row & 7))] = pk;
        }
    }

    // ---- hoisted constants ----
    const uint4* Adl = dl4 + (cl << 7);
    const int sw = cl & 7;
    float ivv[4];
    #pragma unroll
    for (int r = 0; r < 4; ++r) ivv[r] = inv[a0 + 4 * q + r];
    const uint4* bhp = &s_hh[cl & 3][(cl >> 2) + q];
    const uint4* blp = &s_ll[cl & 3][(cl >> 2) + q];
    unsigned int* hw = (unsigned int*)s_hh;
    unsigned int* lw = (unsigned int*)s_ll;

    // ---- pass -1: initial full conv into cml (16 windows x 1024 t) ----
    // Window w stages t in [wb, wb+1539) from registers (prefetched under the
    // previous window's MFMA, T14), then each wave runs one 128-t super
    // (c0 = 2*wave <= 14 -> chunks 2w..2w+1 of window). Order == k_conv.
    {
        const float* xb = x + b * T_;
        float cur[4], nxt[4];
        #pragma unroll
        for (int s = 0; s < 4; ++s) {
            const int e = tid + 512 * s;
            cur[s] = (e < 1539) ? xb[e] : 0.f;      // window 0: t = e < T_
        }
        for (int w = 0; w < 16; ++w) {
            const int wb = w << 10;
            if (w) __syncthreads();          // previous window's reads done
            #pragma unroll
            for (int s = 0; s < 4; ++s) {
                const int e = tid + 512 * s;
                if (e < 1539) {
                    float xv = cur[s];
                    unsigned int pw = packhl(xv);
                    unsigned int hword = (pw & 0xffffu) * 0x10001u;
                    unsigned int lword = (pw >> 16) * 0x10001u;
                    #pragma unroll
                    for (int sh = 0; sh < 4; ++sh) {
                        int i = e - sh;
                        if (i >= 0 && i < 1536) { hw[sh * 1640 + i] = hword; lw[sh * 1640 + i] = lword; }
                    }
                }
            }
            __syncthreads();
            if (w + 1 < 16) {                // T14: issue next window's loads now
                const int wb2 = (w + 1) << 10;
                #pragma unroll
                for (int s = 0; s < 4; ++s) {
                    const int e = tid + 512 * s;
                    const int t = wb2 + e;
                    nxt[s] = (e < 1539 && t < T_) ? xb[t] : 0.f;
                }
            }
            run_super(bhp, blp, Adl, sw, 2 * wave, wb, w << 4,
                      cml, ivv, a0, q, cl);
            #pragma unroll
            for (int s = 0; s < 4; ++s) cur[s] = nxt[s];
        }
    }
    __syncthreads();   // cml complete block-wide

    // ---- initial rm winner (replaces k_tables): 16 rows -> 1 u64 ----
    {
        #pragma unroll
        for (int rr = 0; rr < 2; ++rr) {
            const int rl = wave * 2 + rr;
            const u64* p = cml + (rl << 8);
            u64 m = umax64(umax64(p[lane], p[lane + 64]),
                           umax64(p[lane + 128], p[lane + 192]));
            #pragma unroll
            for (int o = 32; o > 0; o >>= 1) m = umax64(m, shfl_down_u64(m, o));
            if (lane == 0) red16[rl] = m;
        }
        __syncthreads();
        if (wave == 0) {
            u64 wv = (lane < 16) ? red16[lane] : 0ull;
            #pragma unroll
            for (int o = 8; o > 0; o >>= 1) wv = umax64(wv, shfl_xor_u64(wv, o));
            if (lane == 0) st_au64(&rmW[b * 32 + ag], wv);
        }
    }
    unsigned int gen = 1;
    b_barrier(slots, ag, gen); ++gen;

    for (int it = 0; it < NIT_; ++it) {
        // ---- phase A: global argmax from 32 block winners (no barriers) ----
        const u64* rwp = rmW + ((it & 1) << 8) + b * 32;
        u64 am = ld_au64(&rwp[lane & 31]);
        #pragma unroll
        for (int o = 16; o > 0; o >>= 1) am = umax64(am, shfl_xor_u64(am, o));
        const unsigned int enc = (unsigned int)(am >> 32);
        const unsigned int flat = ~(unsigned int)am;
        const int asel = (int)((flat >> 14) & (NA_ - 1));
        const int tsel = (int)(flat & (T_ - 1));
        const float v = decf(enc);
        if (tid == 0) { selAL[it] = asel; selTL[it] = tsel; selVL[it] = v; }
        if (ag == 0 && tid == 0) {
            selA[it * B_ + b] = asel;
            selT[it * B_ + b] = tsel;
            selV[it * B_ + b] = v;
        }
        if (it == NIT_ - 1) break;   // B-E would only feed a nonexistent iter
        const int L = min(A_, (T_ - 1) - tsel);   // reference truncation quirk
        const float vv = v * inv[asel];

        const float* xrPrev = (it == 0) ? x : ((it & 1) ? xrB : xrA);
        float*       xrNext = (it & 1) ? xrA : xrB;

        // ---- phase C loads hoisted (T14): issue before phase B ----
        int ab = 0, nch = 0, NS = 0;
        float cbuf[4];
        if (L > 0) {
            const int tbeg = max(0, tsel - (A_ - 1));
            const int tend = tsel + L;               // <= 16383
            ab = tbeg & ~63;
            const int ae = (tend + 63) & ~63;        // <= T_
            const int W = ae - ab;                   // <= 1088
            nch = W >> 6;                            // <= 17
            NS = W + 512;                            // <= 1600
            #pragma unroll
            for (int s = 0; s < 4; ++s) {
                const int e = tid + 512 * s;
                const int t = ab + e;
                cbuf[s] = (e < NS + 3 && t < T_) ? ld_af(&xrPrev[b * T_ + t]) : 0.f;
            }
        }

        // ---- phase B: xr ping-pong slice [ag*512, +512) (agent ld/st) ----
        {
            int t = ag * 512 + tid;
            float xv = ld_af(&xrPrev[b * T_ + t]);
            int o = t - tsel;
            if (L > 0 && o >= 0 && o < L) xv = fmaf(-vv, d[asel * A_ + o], xv);
            st_af(&xrNext[b * T_ + t], xv);
        }

        if (L > 0) {
            // ---- phase C: patch+convert from registers, 4 shifted LDS writes ----
            #pragma unroll
            for (int s = 0; s < 4; ++s) {
                const int e = tid + 512 * s;
                if (e < NS + 3) {
                    float xv = cbuf[s];
                    int o = (ab + e) - tsel;
                    if (o >= 0 && o < L) xv = fmaf(-vv, d[asel * A_ + o], xv);
                    unsigned int pw = packhl(xv);
                    unsigned int hword = (pw & 0xffffu) * 0x10001u;
                    unsigned int lword = (pw >> 16) * 0x10001u;
                    #pragma unroll
                    for (int sh = 0; sh < 4; ++sh) {
                        int i = e - sh;
                        if (i >= 0 && i < NS) { hw[sh * 1640 + i] = hword; lw[sh * 1640 + i] = lword; }
                    }
                }
            }
            __syncthreads();

            // ---- phase D: balanced contiguous runs over waves ----
            // wave owns chunks [lo, hi); pairs as supers, remainder single.
            {
                const int lo = (wave * nch) >> 3;
                const int hi = ((wave + 1) * nch) >> 3;
                int c = lo;
                for (; c + 1 < hi; c += 2)
                    run_super(bhp, blp, Adl, sw, c, ab, ab >> 6,
                              cml, ivv, a0, q, cl);
                if (c < hi)
                    run_single(bhp, blp, Adl, sw, c, ab, ab >> 6,
                               cml, ivv, a0, q, cl);
            }
            __syncthreads();   // cml writes visible block-wide
        }

        // ---- phase E: 16 row maxima -> block winner -> rmW ----
        #pragma unroll
        for (int rr = 0; rr < 2; ++rr) {
            const int rl = wave * 2 + rr;
            const u64* p = cml + (rl << 8);
            u64 m = umax64(umax64(p[lane], p[lane + 64]),
                           umax64(p[lane + 128], p[lane + 192]));
            #pragma unroll
            for (int o = 32; o > 0; o >>= 1) m = umax64(m, shfl_down_u64(m, o));
            if (lane == 0) red16[rl] = m;
        }
        __syncthreads();
        if (wave == 0) {
            u64 wv = (lane < 16) ? red16[lane] : 0ull;
            #pragma unroll
            for (int o = 8; o > 0; o >>= 1) wv = umax64(wv, shfl_xor_u64(wv, o));
            if (lane == 0) st_au64(&rmW[(((it + 1) & 1) << 8) + b * 32 + ag], wv);
        }

        b_barrier(slots, ag, gen); ++gen;
    }

    // ---- final reconstruct (folded k_final) from block-local sel history ----
    __syncthreads();   // selAL[31] visible
    {
        const int t = ag * 512 + tid;
        const int gid = b * T_ + t;
        float r = x[gid];
        float rec = 0.f;
        for (int k = 0; k < NIT_; ++k) {       // sequential: reference fp order
            int a  = selAL[k] & (NA_ - 1);
            int ts = selTL[k] & (T_ - 1);
            float vvl = selVL[k] * inv[a];
            int o = t - ts;
            int Lf = min(A_, (T_ - 1) - ts);
            if (o >= 0 && o < Lf) {
                float c = vvl * d[a * A_ + o];
                r -= c;
                rec += c;
            }
        }
        out[gid] = r;
        out[B_ * T_ + gid] = rec;
    }
}

// ================= fallback path (unchanged, proven r3 structure) =================

__global__ __launch_bounds__(512) void k_conv(const float* __restrict__ x,
                                              const unsigned int* __restrict__ dpk,
                                              const float* __restrict__ inv,
                                              u64* __restrict__ cm,
                                              float* __restrict__ xrA) {
    __shared__ uint4 s_hh[4][202];
    __shared__ uint4 s_ll[4][202];
    const int tid = threadIdx.x;
    const int wave = tid >> 6, lane = tid & 63;
    const int cl = lane & 15, q = lane >> 4;
    const int wb = blockIdx.x * 256;
    const int gb = blockIdx.z;

    unsigned int* hw = (unsigned int*)s_hh;
    unsigned int* lw = (unsigned int*)s_ll;
    for (int e = tid; e < 776; e += 512) {
        int t = wb + e;
        float xv = (t < T_) ? x[gb * T_ + t] : 0.f;
        if (blockIdx.y == 0 && e < 256) xrA[gb * T_ + wb + e] = xv;
        unsigned int pw = packhl(xv);
        unsigned int hword = (pw & 0xffffu) * 0x10001u;
        unsigned int lword = (pw >> 16) * 0x10001u;
        #pragma unroll
        for (int s = 0; s < 4; ++s) {
            int i = e - s;
            if (i >= 0 && i < 772) { hw[s * 808 + i] = hword; lw[s * 808 + i] = lword; }
        }
    }
    __syncthreads();

    const int a_base = blockIdx.y * 128 + (wave & 1) * 64;
    const int t0l = (wave >> 1) * 64;
    const unsigned int* Ap[4];
    #pragma unroll
    for (int at = 0; at < 4; ++at)
        Ap[at] = dpk + ((a_base + 16 * at + cl) << 9) + 4 * q;
    const uint4* bhp = &s_hh[cl & 3][(t0l >> 2) + (cl >> 2) + q];
    const uint4* blp = &s_ll[cl & 3][(t0l >> 2) + (cl >> 2) + q];

    f32x4 acc[4][4];
    const f32x4 zero = {0.f, 0.f, 0.f, 0.f};
    #pragma unroll
    for (int at = 0; at < 4; ++at)
        #pragma unroll
        for (int tt = 0; tt < 4; ++tt) acc[at][tt] = zero;

    for (int j0 = 0; j0 < A_; j0 += 16) {
        Frag Af[4], bh[4], bl[4];
        #pragma unroll
        for (int at = 0; at < 4; ++at) Af[at].u = *(const uint4*)(Ap[at] + j0);
        #pragma unroll
        for (int tt = 0; tt < 4; ++tt) {
            bh[tt].u = bhp[4 * tt + (j0 >> 2)];
            bl[tt].u = blp[4 * tt + (j0 >> 2)];
        }
        #pragma unroll
        for (int tt = 0; tt < 4; ++tt)
            #pragma unroll
            for (int at = 0; at < 4; ++at)
                acc[at][tt] = __builtin_amdgcn_mfma_f32_16x16x32_bf16(Af[at].f, bh[tt].f, acc[at][tt], 0, 0, 0);
        #pragma unroll
        for (int tt = 0; tt < 4; ++tt)
            #pragma unroll
            for (int at = 0; at < 4; ++at)
                acc[at][tt] = __builtin_amdgcn_mfma_f32_16x16x32_bf16(Af[at].f, bl[tt].f, acc[at][tt], 0, 0, 0);
    }

    const int t0 = wb + t0l;
    const int ch = t0 >> 6;
    #pragma unroll
    for (int at = 0; at < 4; ++at) {
        #pragma unroll
        for (int r = 0; r < 4; ++r) {
            const int atom = a_base + 16 * at + 4 * q + r;
            const float iv = inv[atom];
            u64 m = 0ull;
            #pragma unroll
            for (int tt = 0; tt < 4; ++tt) {
                int t = t0 + 16 * tt + cl;
                m = umax64(m, enc64(acc[at][tt][r] * iv, (unsigned int)(atom * T_ + t)));
            }
            m = umax64(m, shfl_xor_u64(m, 1));
            m = umax64(m, shfl_xor_u64(m, 2));
            m = umax64(m, shfl_xor_u64(m, 4));
            m = umax64(m, shfl_xor_u64(m, 8));
            if (cl == 0)
                cm[((size_t)(gb * NA_ + atom) << 8) + ch] = m;
        }
    }
}

__global__ __launch_bounds__(256) void k_tables(const u64* __restrict__ cm, u64* __restrict__ rm) {
    const int row = blockIdx.x * 4 + (threadIdx.x >> 6);
    const int lane = threadIdx.x & 63;
    const u64* p = cm + ((size_t)row << 8);
    u64 m = 0ull;
    #pragma unroll
    for (int k = 0; k < 4; ++k) m = umax64(m, p[lane + 64 * k]);
    #pragma unroll
    for (int o = 32; o > 0; o >>= 1) m = umax64(m, shfl_down_u64(m, o));
    if (lane == 0) rm[row] = m;
}

__global__ __launch_bounds__(512) void k_it(const float* __restrict__ xrPrev,
                                            float* __restrict__ xrNext,
                                            const float* __restrict__ d,
                                            const float* __restrict__ inv,
                                            const unsigned int* __restrict__ dpk,
                                            u64* __restrict__ cm,
                                            const u64* __restrict__ rmPrev,
                                            u64* __restrict__ rmNext,
                                            int* __restrict__ selA,
                                            int* __restrict__ selT,
                                            float* __restrict__ selV,
                                            int it) {
    __shared__ u64 red8[8];
    __shared__ uint4 s_hh[4][410];
    __shared__ uint4 s_ll[4][410];
    __shared__ uint4 dl4[16 * 128];
    const int ag = blockIdx.x, b = blockIdx.y, tid = threadIdx.x;
    const int wave = tid >> 6, lane = tid & 63;
    const int cl = lane & 15, q = lane >> 4;
    const int a0 = ag * 16;

    {
        const uint4* gsrc = (const uint4*)(dpk + (a0 << 9));
        #pragma unroll
        for (int s = 0; s < 4; ++s) {
            int i = tid + 512 * s;
            int row = i >> 7, c4 = i & 127;
            dl4[(row << 7) | (c4 ^ (row & 7))] = gsrc[i];
        }
    }

    const u64* rp = rmPrev + b * NA_;
    u64 am = rp[tid];
    #pragma unroll
    for (int o = 32; o > 0; o >>= 1) am = umax64(am, shfl_xor_u64(am, o));
    if (lane == 0) red8[wave] = am;
    __syncthreads();
    u64 win = red8[0];
    #pragma unroll
    for (int w2 = 1; w2 < 8; ++w2) win = umax64(win, red8[w2]);
    const unsigned int enc = (unsigned int)(win >> 32);
    const unsigned int flat = ~(unsigned int)win;
    const int asel = (int)((flat >> 14) & (NA_ - 1));
    const int tsel = (int)(flat & (T_ - 1));
    const float v = decf(enc);
    if (ag == 0 && tid == 0) {
        selA[it * B_ + b] = asel;
        selT[it * B_ + b] = tsel;
        selV[it * B_ + b] = v;
    }
    const int L = min(A_, (T_ - 1) - tsel);
    const float vv = v * inv[asel];

    {
        int t = ag * 512 + tid;
        float xv = xrPrev[b * T_ + t];
        int o = t - tsel;
        if (L > 0 && o >= 0 && o < L) xv = fmaf(-vv, d[asel * A_ + o], xv);
        xrNext[b * T_ + t] = xv;
    }

    if (L > 0) {
        const int tbeg = max(0, tsel - (A_ - 1));
        const int tend = tsel + L;
        const int ab = tbeg & ~63;
        const int ae = (tend + 63) & ~63;
        const int W = ae - ab;
        const int nch = W >> 6;
        const int NS = W + 512;

        unsigned int* hw = (unsigned int*)s_hh;
        unsigned int* lw = (unsigned int*)s_ll;
        for (int e = tid; e < NS + 3; e += 512) {
            int t = ab + e;
            float xv = (t < T_) ? xrPrev[b * T_ + t] : 0.f;
            int o = t - tsel;
            if (o >= 0 && o < L) xv = fmaf(-vv, d[asel * A_ + o], xv);
            unsigned int pw = packhl(xv);
            unsigned int hword = (pw & 0xffffu) * 0x10001u;
            unsigned int lword = (pw >> 16) * 0x10001u;
            #pragma unroll
            for (int s = 0; s < 4; ++s) {
                int i = e - s;
                if (i >= 0 && i < NS) { hw[s * 1640 + i] = hword; lw[s * 1640 + i] = lword; }
            }
        }
        __syncthreads();

        const uint4* Adl = dl4 + (cl << 7);
        const int sw = cl & 7;
        float ivv[4];
        #pragma unroll
        for (int r = 0; r < 4; ++r) ivv[r] = inv[a0 + 4 * q + r];
        const uint4* bhp = &s_hh[cl & 3][(cl >> 2) + q];
        const uint4* blp = &s_ll[cl & 3][(cl >> 2) + q];

        for (int c = wave; c < nch; c += 8) {
            f32x4 acc[4];
            const f32x4 zero = {0.f, 0.f, 0.f, 0.f};
            #pragma unroll
            for (int tt = 0; tt < 4; ++tt) acc[tt] = zero;

            Frag bh[4], bl[4];
            #pragma unroll
            for (int pp = 0; pp < 4; ++pp) {
                bh[pp].u = bhp[16 * c + 4 * pp];
                bl[pp].u = blp[16 * c + 4 * pp];
            }
            for (int j0 = 0; j0 < A_; j0 += 64) {
                #pragma unroll
                for (int u = 0; u < 4; ++u) {
                    const int jj = j0 + 16 * u;
                    Frag Af;
                    Af.u = Adl[(q + (jj >> 2)) ^ sw];
                    #pragma unroll
                    for (int tt = 0; tt < 4; ++tt)
                        acc[tt] = __builtin_amdgcn_mfma_f32_16x16x32_bf16(Af.f, bh[(u + tt) & 3].f, acc[tt], 0, 0, 0);
                    #pragma unroll
                    for (int tt = 0; tt < 4; ++tt)
                        acc[tt] = __builtin_amdgcn_mfma_f32_16x16x32_bf16(Af.f, bl[(u + tt) & 3].f, acc[tt], 0, 0, 0);
                    bh[u].u = bhp[16 * c + (jj >> 2) + 16];
                    bl[u].u = blp[16 * c + (jj >> 2) + 16];
                }
            }
            #pragma unroll
            for (int r = 0; r < 4; ++r) {
                const int atom = a0 + 4 * q + r;
                u64 mm = 0ull;
                #pragma unroll
                for (int tt = 0; tt < 4; ++tt) {
                    int t = ab + 64 * c + 16 * tt + cl;
                    mm = umax64(mm, enc64(acc[tt][r] * ivv[r], (unsigned int)(atom * T_ + t)));
                }
                mm = umax64(mm, shfl_xor_u64(mm, 1));
                mm = umax64(mm, shfl_xor_u64(mm, 2));
                mm = umax64(mm, shfl_xor_u64(mm, 4));
                mm = umax64(mm, shfl_xor_u64(mm, 8));
                if (cl == 0)
                    cm[((size_t)(b * NA_ + atom) << 8) + (ab >> 6) + c] = mm;
            }
        }
        __syncthreads();
    }

    #pragma unroll
    for (int rr = 0; rr < 2; ++rr) {
        const int row = a0 + wave * 2 + rr;
        const u64* p = cm + ((size_t)(b * NA_ + row) << 8);
        u64 m = umax64(umax64(p[lane], p[lane + 64]),
                       umax64(p[lane + 128], p[lane + 192]));
        #pragma unroll
        for (int o = 32; o > 0; o >>= 1) m = umax64(m, shfl_down_u64(m, o));
        if (lane == 0) rmNext[b * NA_ + row] = m;
    }
}

__global__ void s_init(const float* __restrict__ x, float* __restrict__ xr,
                       u64* __restrict__ cand) {
    int i = blockIdx.x * 256 + threadIdx.x;
    if (i < B_ * T_) xr[i] = x[i];
    if (i < B_) cand[i] = 0ull;
}
__global__ __launch_bounds__(256) void s_scan(const float* __restrict__ xr,
                                              const float* __restrict__ d,
                                              const float* __restrict__ inv,
                                              u64* __restrict__ cand) {
    __shared__ float dLs[A_];
    __shared__ u64 redU[256];
    const int aB = blockIdx.x, b = blockIdx.y, tid = threadIdx.x;
    const float iv = inv[aB];
    for (int i = tid; i < A_; i += 256) dLs[i] = d[aB * A_ + i] * iv;
    __syncthreads();
    const float* xb = xr + b * T_;
    u64 best = 0ull;
    for (int t = tid; t < T_; t += 256) {
        float acc = 0.f;
        int lim = min(A_, T_ - t);
        for (int i = 0; i < lim; ++i) acc = fmaf(dLs[i], xb[t + i], acc);
        best = umax64(best, enc64(acc, (unsigned int)(aB * T_ + t)));
    }
    redU[tid] = best;
    __syncthreads();
    for (int s = 128; s > 0; s >>= 1) {
        if (tid < s) redU[tid] = umax64(redU[tid], redU[tid + s]);
        __syncthreads();
    }
    if (tid == 0) atomicMax(&cand[b], redU[0]);
}
__global__ void s_apply(float* __restrict__ xr, const float* __restrict__ d,
                        const float* __restrict__ inv, u64* __restrict__ cand,
                        int* selA, int* selT, float* selV, int it) {
    const int b = blockIdx.x, tid = threadIdx.x;
    u64 win = cand[b];
    unsigned int enc = (unsigned int)(win >> 32);
    unsigned int flat = ~(unsigned int)win;
    int a = (int)((flat >> 14) & (NA_ - 1)), t = (int)(flat & (T_ - 1));
    float v = decf(enc);
    if (tid == 0) { selA[it * B_ + b] = a; selT[it * B_ + b] = t; selV[it * B_ + b] = v; }
    float vvl = v * inv[a];
    int L = min(A_, (T_ - 1) - t);
    for (int o = tid; o < L; o += 256) xr[b * T_ + t + o] -= vvl * d[a * A_ + o];
    if (tid == 0) cand[b] = 0ull;
}

__global__ __launch_bounds__(256) void k_final(const float* __restrict__ x,
                                               const float* __restrict__ d,
                                               const int* __restrict__ selA,
                                               const int* __restrict__ selT,
                                               const float* __restrict__ selV,
                                               const float* __restrict__ inv,
                                               float* __restrict__ out) {
    const int gid = blockIdx.x * 256 + threadIdx.x;
    const int b = gid >> 14;
    const int t = gid & (T_ - 1);
    float r = x[gid];
    float rec = 0.f;
    for (int k = 0; k < NIT_; ++k) {           // sequential: reference fp order
        int a  = selA[k * B_ + b] & (NA_ - 1);
        int ts = selT[k * B_ + b] & (T_ - 1);
        float vvl = selV[k * B_ + b] * inv[a];
        int o = t - ts;
        int L = min(A_, (T_ - 1) - ts);
        if (o >= 0 && o < L) {
            float c = vvl * d[a * A_ + o];
            r -= c;
            rec += c;
        }
    }
    out[gid] = r;
    out[B_ * T_ + gid] = rec;
}

extern "C" void kernel_launch(void* const* d_in, const int* in_sizes, int n_in,
                              void* d_out, int out_size, void* d_ws, size_t ws_size,
                              hipStream_t stream) {
    const float* x = (const float*)d_in[0];
    const float* d = (const float*)d_in[1];
    float* out = (float*)d_out;
    float* ws = (float*)d_ws;
    const size_t wsf = ws_size / sizeof(float);

    float* inv  = ws + OFF_INV;
    int*   selA = (int*)(ws + OFF_SELA);
    int*   selT = (int*)(ws + OFF_SELT);
    float* selV = ws + OFF_SELV;

    if (wsf < (size_t)S_NEED) return;   // hopeless

    const bool persistOK = wsf >= (size_t)PERS_NEED;
    unsigned int* bar = persistOK ? (unsigned int*)(ws + OFF_BAR) : (unsigned int*)0;

    k_inv<<<dim3(NA_), dim3(64), 0, stream>>>(d, inv, bar);

    if (wsf >= (size_t)MAIN_NEED) {
        u64* cm  = (u64*)(ws + OFF_CM);
        u64* rmA = (u64*)(ws + OFF_RMA);
        u64* rmB = (u64*)(ws + OFF_RMB);
        float* xrA = ws + OFF_XRA;
        float* xrB = ws + OFF_XRB;
        unsigned int* dpk = (unsigned int*)(ws + OFF_DPK);

        if (persistOK) {
            u64* rmW = (u64*)(ws + OFF_RMA);    // u64[2][256]
            k_persist<<<dim3(NA_ / 16, B_), dim3(512), 0, stream>>>(x, xrA, xrB, d, inv,
                                                                    rmW, selA, selT, selV,
                                                                    bar, out);
            return;   // out fully written by k_persist
        }

        k_split_d<<<dim3(NA_ * A_ / 256), dim3(256), 0, stream>>>(d, dpk);
        k_conv<<<dim3(T_ / 256, NA_ / 128, B_), dim3(512), 0, stream>>>(x, dpk, inv, cm, xrA);
        k_tables<<<dim3(B_ * NA_ / 4), dim3(256), 0, stream>>>(cm, rmA);
        for (int it = 0; it < NIT_; ++it) {
            const float* xp = (it & 1) ? xrB : xrA;
            float*       xn = (it & 1) ? xrA : xrB;
            const u64*   ro = (it & 1) ? rmB : rmA;
            u64*         rn = (it & 1) ? rmA : rmB;
            k_it<<<dim3(NA_ / 16, B_), dim3(512), 0, stream>>>(xp, xn, d, inv, dpk,
                                                               cm, ro, rn,
                                                               selA, selT, selV, it);
        }
    } else {
        float* xr = ws + OFF_SXR;
        u64* cand = (u64*)(ws + OFF_SCAND);
        s_init<<<dim3((B_ * T_ + 255) / 256), dim3(256), 0, stream>>>(x, xr, cand);
        for (int it = 0; it < NIT_; ++it) {
            s_scan<<<dim3(NA_, B_), dim3(256), 0, stream>>>(xr, d, inv, cand);
            s_apply<<<dim3(B_), dim3(256), 0, stream>>>(xr, d, inv, cand, selA, selT, selV, it);
        }
    }

    k_final<<<dim3(B_ * T_ / 256), dim3(256), 0, stream>>>(x, d, selA, selT, selV, inv, out);
}

// Round 11
// 706.424 us; speedup vs baseline: 1.1484x; 1.1484x over previous
//
#include <hip/hip_runtime.h>
#include <cstdint>

#define B_    8
#define T_    16384
#define NA_   512
#define A_    512
#define NIT_  32
#define EPSV  1e-8f

typedef unsigned long long u64;
typedef __attribute__((ext_vector_type(8))) short bf16x8;
typedef __attribute__((ext_vector_type(4))) float f32x4;

union Frag { uint4 u; bf16x8 f; };

#define MFMA16(a, b, c) __builtin_amdgcn_mfma_f32_16x16x32_bf16((a), (b), (c), 0, 0, 0)

// ws float-offset layout
#define OFF_INV   0
#define OFF_SELA  512
#define OFF_SELT  768
#define OFF_SELV  1024
#define OFF_CM    1280        // u64[8*512*256] (fallback path only)
#define OFF_RMA   2098432     // persistent: rmW u64[2][256]; fallback: rm u64[4096]
#define OFF_RMB   2106624     // u64[4096] (fallback)
#define OFF_XRA   2114816     // f32[8*16384]
#define OFF_XRB   2245888     // f32[8*16384]
#define OFF_DPK   2376960     // u32[512*512]  (fallback path only)
#define MAIN_NEED 2639104     // launch-loop requirement
#define OFF_BAR   2639104     // u32 gen-slots: 8 batches x 32 blocks x 16-dword stride
#define PERS_NEED (OFF_BAR + 4096)
// compact fallback layout
#define OFF_SXR   OFF_CM
#define OFF_SCAND (OFF_CM + 131072)
#define S_NEED    (OFF_SCAND + 16)

__device__ __forceinline__ unsigned int encf(float f) {
    unsigned int u = __float_as_uint(f);
    return (u & 0x80000000u) ? ~u : (u | 0x80000000u);
}
__device__ __forceinline__ float decf(unsigned int e) {
    unsigned int u = (e & 0x80000000u) ? (e & 0x7fffffffu) : ~e;
    return __uint_as_float(u);
}
__device__ __forceinline__ u64 umax64(u64 a, u64 b) { return a > b ? a : b; }
__device__ __forceinline__ u64 enc64(float v, unsigned int flat) {
    return (((u64)encf(v)) << 32) | (unsigned int)~flat;
}
__device__ __forceinline__ u64 shfl_xor_u64(u64 v, int mask) {
    unsigned int lo = (unsigned int)v, hi = (unsigned int)(v >> 32);
    lo = __shfl_xor(lo, mask, 64);
    hi = __shfl_xor(hi, mask, 64);
    return (((u64)hi) << 32) | lo;
}
__device__ __forceinline__ u64 shfl_down_u64(u64 v, int off) {
    unsigned int lo = (unsigned int)v, hi = (unsigned int)(v >> 32);
    lo = __shfl_down(lo, off, 64);
    hi = __shfl_down(hi, off, 64);
    return (((u64)hi) << 32) | lo;
}
// bf16 round-to-nearest-even from fp32
__device__ __forceinline__ unsigned short f2bf(float v) {
    unsigned int u = __float_as_uint(v);
    return (unsigned short)((u + 0x7fffu + ((u >> 16) & 1u)) >> 16);
}
// float -> (hi-bf16 | lo-bf16<<16), bit-identical to k_split_d
__device__ __forceinline__ unsigned int packhl(float v) {
    unsigned short hb = f2bf(v);
    unsigned short lb = f2bf(v - __uint_as_float((unsigned int)hb << 16));
    return (unsigned int)hb | ((unsigned int)lb << 16);
}

// agent-scope (cross-XCD coherent, L2-bypassing) data ops (r5-proven).
__device__ __forceinline__ float ld_af(const float* p) {
    return __hip_atomic_load(p, __ATOMIC_RELAXED, __HIP_MEMORY_SCOPE_AGENT);
}
__device__ __forceinline__ void st_af(float* p, float v) {
    __hip_atomic_store(p, v, __ATOMIC_RELAXED, __HIP_MEMORY_SCOPE_AGENT);
}
__device__ __forceinline__ u64 ld_au64(const u64* p) {
    return __hip_atomic_load(p, __ATOMIC_RELAXED, __HIP_MEMORY_SCOPE_AGENT);
}
__device__ __forceinline__ void st_au64(u64* p, u64 v) {
    __hip_atomic_store(p, v, __ATOMIC_RELAXED, __HIP_MEMORY_SCOPE_AGENT);
}

// per-b 32-block distributed-flag barrier (r10-proven).
__device__ __forceinline__ void b_barrier(unsigned int* slots, int ag, unsigned int gen) {
    __syncthreads();
    const int tid = threadIdx.x;
    if (tid == 0)
        __hip_atomic_store(&slots[ag << 4], gen, __ATOMIC_RELAXED, __HIP_MEMORY_SCOPE_AGENT);
    if (tid < 64) {
        const unsigned int* sp = &slots[(tid & 31) << 4];
        int spins = 0;
        while (__hip_atomic_load(sp, __ATOMIC_RELAXED, __HIP_MEMORY_SCOPE_AGENT) < gen) {
            __builtin_amdgcn_s_sleep(1);
            if (++spins > (1 << 20)) break;   // safety valve
        }
    }
    __syncthreads();
    asm volatile("" ::: "memory");
}

// lp fragment load: 4 x b32 (per-lane parity defeats 16B alignment).
__device__ __forceinline__ uint4 lp4(const unsigned int* lps, int w) {
    uint4 r;
    r.x = lps[w]; r.y = lps[w + 1]; r.z = lps[w + 2]; r.w = lps[w + 3];
    return r;
}

// ---------------------------------------------------------------------------
// 3-term hi/lo scheme (r11): conv = (hi_d+lo_d)*hi_x  +  hi_d*lo_x
// (lo_d*lo_x dropped: ~2^-16 relative, far below bf16 rounding floor).
//   P1 (32 K-steps): A = dl4 (hi_d|lo_d interleaved), B = s_hh (hi_x dup).
//   P2 (16 K-steps): A = ah4 (hi_d pairs, dense),     B = lp (lo_x pairs).
// P2 mapping (verified): A2 uint4 v=4*j2+q <-> taps 32*j2+8q..+7, row=cl.
//   B2 lane (n=cl,q) K-slot kk <-> lo_x[t0+16m + 8q + cl + kk], m=g+2*j2;
//   ushort index X = 64c + 16m + 8q + cl; parity copy s=X&1=cl&1; w = X>>1.
// P2 rotation: slot (g+2*j2)&DEPTH-1; 2 refills/step feed step j2+1 (r7
// lesson: refills are consumed by later steps; ONLY the final step's refills
// are dead -> in-bounds junk, never consumed). j2 unrolled by 4 (super) / 2
// (single) so all slot indices constant-fold (rule #20).
// ---------------------------------------------------------------------------

// one 128-t super-chunk (chunks c0, c0+1): 8 output t-tiles.
// P1: 256 MFMA; P2: 128 MFMA. (was 512 -> -25%)
__device__ __forceinline__ void run_super(const uint4* bhp,
                                          const uint4* Adl, int sw,
                                          const unsigned int* lps,
                                          const uint4* A2p,
                                          int c0, int tbase, int chbase,
                                          u64* cml, const float* ivv,
                                          int a0, int q, int cl) {
    const int base = c0 << 4;
    f32x4 acc[8];
    const f32x4 zero = {0.f, 0.f, 0.f, 0.f};
    #pragma unroll
    for (int g = 0; g < 8; ++g) acc[g] = zero;

    // ---- P1: (hi_d,lo_d) x dup(hi_x), 32 steps, 8-deep rotating file ----
    {
        Frag bh[8];
        #pragma unroll
        for (int pp = 0; pp < 8; ++pp) bh[pp].u = bhp[base + 4 * pp];
        for (int js0 = 0; js0 < 32; js0 += 8) {
            #pragma unroll
            for (int ju = 0; ju < 8; ++ju) {
                const int js = js0 + ju;
                Frag Af;
                Af.u = Adl[(q + 4 * js) ^ sw];
                #pragma unroll
                for (int g = 0; g < 8; ++g)
                    acc[g] = MFMA16(Af.f, bh[(g + ju) & 7].f, acc[g]);
                bh[ju].u = bhp[base + 4 * (js + 8)];   // in-bounds (<=396<410)
            }
        }
    }
    // ---- P2: hi_d pairs x lo_x pairs, 16 steps, 8-deep file, 2 refills ----
    {
        const int bb = 32 * c0 + 4 * q + (cl >> 1);
        Frag b2[8];
        #pragma unroll
        for (int m = 0; m < 8; ++m) b2[m].u = lp4(lps, bb + 8 * m);
        for (int j2b = 0; j2b < 4; ++j2b) {
            #pragma unroll
            for (int j2u = 0; j2u < 4; ++j2u) {
                const int j2 = 4 * j2b + j2u;
                Frag A2;
                A2.u = A2p[(4 * j2 + q) ^ sw];
                #pragma unroll
                for (int g = 0; g < 8; ++g)
                    acc[g] = MFMA16(A2.f, b2[(g + 2 * j2u) & 7].f, acc[g]);
                // refills feed step j2+1 (m-range [2j2+2, 2j2+9]); last step's
                // refills are dead but read in-bounds (lp sized 816 dwords).
                b2[(2 * j2u) & 7].u     = lp4(lps, bb + 8 * (2 * j2 + 8));
                b2[(2 * j2u + 1) & 7].u = lp4(lps, bb + 8 * (2 * j2 + 9));
            }
        }
    }
    #pragma unroll
    for (int r = 0; r < 4; ++r) {
        const int atom4 = 4 * q + r;
        const int atom = a0 + atom4;
        u64 m0 = 0ull, m1 = 0ull;
        #pragma unroll
        for (int g = 0; g < 4; ++g) {
            int t = tbase + 64 * c0 + 16 * g + cl;
            m0 = umax64(m0, enc64(acc[g][r] * ivv[r], (unsigned int)(atom * T_ + t)));
        }
        #pragma unroll
        for (int g = 4; g < 8; ++g) {
            int t = tbase + 64 * c0 + 16 * g + cl;
            m1 = umax64(m1, enc64(acc[g][r] * ivv[r], (unsigned int)(atom * T_ + t)));
        }
        m0 = umax64(m0, shfl_xor_u64(m0, 1));
        m0 = umax64(m0, shfl_xor_u64(m0, 2));
        m0 = umax64(m0, shfl_xor_u64(m0, 4));
        m0 = umax64(m0, shfl_xor_u64(m0, 8));
        m1 = umax64(m1, shfl_xor_u64(m1, 1));
        m1 = umax64(m1, shfl_xor_u64(m1, 2));
        m1 = umax64(m1, shfl_xor_u64(m1, 4));
        m1 = umax64(m1, shfl_xor_u64(m1, 8));
        if (cl == 0) {
            cml[(atom4 << 8) + chbase + c0] = m0;
            cml[(atom4 << 8) + chbase + c0 + 1] = m1;
        }
    }
}

// one 64-t chunk: 4 output t-tiles. P1: 128 MFMA; P2: 64 MFMA. (was 256)
__device__ __forceinline__ void run_single(const uint4* bhp,
                                           const uint4* Adl, int sw,
                                           const unsigned int* lps,
                                           const uint4* A2p,
                                           int c, int tbase, int chbase,
                                           u64* cml, const float* ivv,
                                           int a0, int q, int cl) {
    const int base = c << 4;
    f32x4 acc[4];
    const f32x4 zero = {0.f, 0.f, 0.f, 0.f};
    #pragma unroll
    for (int g = 0; g < 4; ++g) acc[g] = zero;

    // ---- P1: 4-deep rotating file ----
    {
        Frag bh[4];
        #pragma unroll
        for (int pp = 0; pp < 4; ++pp) bh[pp].u = bhp[base + 4 * pp];
        for (int js0 = 0; js0 < 32; js0 += 4) {
            #pragma unroll
            for (int ju = 0; ju < 4; ++ju) {
                const int js = js0 + ju;
                Frag Af;
                Af.u = Adl[(q + 4 * js) ^ sw];
                #pragma unroll
                for (int g = 0; g < 4; ++g)
                    acc[g] = MFMA16(Af.f, bh[(g + ju) & 3].f, acc[g]);
                bh[ju].u = bhp[base + 4 * (js + 4)];
            }
        }
    }
    // ---- P2: 16 steps, 4-deep file, 2 refills/step ----
    {
        const int bb = 32 * c + 4 * q + (cl >> 1);
        Frag b2[4];
        #pragma unroll
        for (int m = 0; m < 4; ++m) b2[m].u = lp4(lps, bb + 8 * m);
        for (int j2b = 0; j2b < 8; ++j2b) {
            #pragma unroll
            for (int j2u = 0; j2u < 2; ++j2u) {
                const int j2 = 2 * j2b + j2u;
                Frag A2;
                A2.u = A2p[(4 * j2 + q) ^ sw];
                #pragma unroll
                for (int g = 0; g < 4; ++g)
                    acc[g] = MFMA16(A2.f, b2[(g + 2 * j2u) & 3].f, acc[g]);
                b2[(2 * j2u) & 3].u     = lp4(lps, bb + 8 * (2 * j2 + 4));
                b2[(2 * j2u + 1) & 3].u = lp4(lps, bb + 8 * (2 * j2 + 5));
            }
        }
    }
    #pragma unroll
    for (int r = 0; r < 4; ++r) {
        const int atom4 = 4 * q + r;
        const int atom = a0 + atom4;
        u64 m0 = 0ull;
        #pragma unroll
        for (int g = 0; g < 4; ++g) {
            int t = tbase + 64 * c + 16 * g + cl;
            m0 = umax64(m0, enc64(acc[g][r] * ivv[r], (unsigned int)(atom * T_ + t)));
        }
        m0 = umax64(m0, shfl_xor_u64(m0, 1));
        m0 = umax64(m0, shfl_xor_u64(m0, 2));
        m0 = umax64(m0, shfl_xor_u64(m0, 4));
        m0 = umax64(m0, shfl_xor_u64(m0, 8));
        if (cl == 0)
            cml[(atom4 << 8) + chbase + c] = m0;
    }
}

// ---------------- inv[a] = 1/(||d_a||+eps); also zero barrier slots ----------------
__global__ __launch_bounds__(64) void k_inv(const float* __restrict__ d, float* __restrict__ inv,
                                            unsigned int* __restrict__ bar) {
    const int a = blockIdx.x, lane = threadIdx.x;
    if (bar && a == 0) {
        for (int i = lane; i < 4096; i += 64) bar[i] = 0u;
    }
    const float* row = d + a * A_;
    float s = 0.f;
    for (int i = lane; i < A_; i += 64) { float v = row[i]; s = fmaf(v, v, s); }
    #pragma unroll
    for (int o = 32; o > 0; o >>= 1) s += __shfl_down(s, o, 64);
    if (lane == 0) inv[a] = 1.0f / (sqrtf(s) + EPSV);
}

// ---------------- d -> packed (hi | lo<<16) (fallback path only) ----------------
__global__ __launch_bounds__(256) void k_split_d(const float* __restrict__ d,
                                                 unsigned int* __restrict__ dpk) {
    int id = blockIdx.x * 256 + threadIdx.x;           // 262144
    dpk[id] = packhl(d[id]);
}

// ---------------- persistent everything-kernel ----------------
// grid (32 ag, 8 b) = 256 blocks; ~115 KB LDS forces 1 block/CU, grid == CU
// count -> co-resident -> software barrier safe (r5-proven).
// r11: 3-term hi/lo scheme (see run_super). s_ll deleted; ah4 (hi-pairs) and
// lp (lo-pairs, even/odd copies via ds_write_b16) added. MFMA count -25%.
__global__ __launch_bounds__(512) void k_persist(const float* __restrict__ x,
                                                 float* __restrict__ xrA,
                                                 float* __restrict__ xrB,
                                                 const float* __restrict__ d,
                                                 const float* __restrict__ inv,
                                                 u64* __restrict__ rmW,
                                                 int* __restrict__ selA,
                                                 int* __restrict__ selT,
                                                 float* __restrict__ selV,
                                                 unsigned int* __restrict__ bar,
                                                 float* __restrict__ out) {
    __shared__ u64 red16[16];
    __shared__ int   selAL[NIT_];
    __shared__ int   selTL[NIT_];
    __shared__ float selVL[NIT_];
    __shared__ uint4 s_hh[4][410];      // hi_x dup, 4 shift copies (P1 B)
    __shared__ unsigned int lp[2][816]; // lo_x pairs, even/odd copies (P2 B)
    __shared__ uint4 ah4[16 * 64];      // hi_d pairs, swizzled (P2 A), 16 KB
    __shared__ uint4 dl4[16 * 128];     // (hi_d|lo_d), swizzled (P1 A), 32 KB
    __shared__ u64  cml[16 * 256];      // block-private cm rows, 32 KB
    const int ag = blockIdx.x, b = blockIdx.y, tid = threadIdx.x;
    const int wave = tid >> 6, lane = tid & 63;
    const int cl = lane & 15, q = lane >> 4;
    const int a0 = ag * 16;
    unsigned int* slots = bar + (b << 9);   // 32 slots x 16-dword stride
    unsigned short* lp0s = (unsigned short*)&lp[0][0];
    unsigned short* lp1s = (unsigned short*)&lp[1][0];

    // ---- one-time staging: dl4 (interleaved) + ah4 (hi pairs), both swizzled ----
    {
        const float4* gsrc = (const float4*)(d + (a0 << 9));
        unsigned int* ah32 = (unsigned int*)ah4;
        #pragma unroll
        for (int s = 0; s < 4; ++s) {
            int i = tid + 512 * s;
            int row = i >> 7, c4 = i & 127;
            float4 f = gsrc[i];
            uint4 pk;
            pk.x = packhl(f.x);
            pk.y = packhl(f.y);
            pk.z = packhl(f.z);
            pk.w = packhl(f.w);
            dl4[(row << 7) | (c4 ^ (row & 7))] = pk;
            // ah: dwords 2c4 (taps 4c4,4c4+1), 2c4+1 (taps 4c4+2,4c4+3)
            unsigned int d0 = (pk.x & 0xffffu) | ((pk.y & 0xffffu) << 16);
            unsigned int d1 = (pk.z & 0xffffu) | ((pk.w & 0xffffu) << 16);
            int u = c4 >> 1;
            int l0 = (2 * c4) & 3;
            int abase = (row << 8) + ((u ^ (row & 7)) << 2);
            ah32[abase + l0] = d0;
            ah32[abase + l0 + 1] = d1;
        }
    }

    // ---- hoisted constants ----
    const uint4* Adl = dl4 + (cl << 7);
    const uint4* A2p = ah4 + (cl << 6);
    const int sw = cl & 7;
    const unsigned int* lps = &lp[cl & 1][0];
    float ivv[4];
    #pragma unroll
    for (int r = 0; r < 4; ++r) ivv[r] = inv[a0 + 4 * q + r];
    const uint4* bhp = &s_hh[cl & 3][(cl >> 2) + q];
    unsigned int* hw = (unsigned int*)s_hh;

    // ---- pass -1: initial full conv into cml (16 windows x 1024 t) ----
    {
        const float* xb = x + b * T_;
        float cur[4], nxt[4];
        #pragma unroll
        for (int s = 0; s < 4; ++s) {
            const int e = tid + 512 * s;
            cur[s] = (e < 1539) ? xb[e] : 0.f;      // window 0: t = e < T_
        }
        for (int w = 0; w < 16; ++w) {
            const int wb = w << 10;
            if (w) __syncthreads();          // previous window's reads done
            #pragma unroll
            for (int s = 0; s < 4; ++s) {
                const int e = tid + 512 * s;
                if (e < 1539) {
                    unsigned int pw = packhl(cur[s]);
                    unsigned int hword = (pw & 0xffffu) * 0x10001u;
                    #pragma unroll
                    for (int sh = 0; sh < 4; ++sh) {
                        int i = e - sh;
                        if (i >= 0 && i < 1536) hw[sh * 1640 + i] = hword;
                    }
                    unsigned short lo = (unsigned short)(pw >> 16);
                    lp0s[e] = lo;
                    if (e > 0) lp1s[e - 1] = lo;
                }
            }
            __syncthreads();
            if (w + 1 < 16) {                // T14: issue next window's loads now
                const int wb2 = (w + 1) << 10;
                #pragma unroll
                for (int s = 0; s < 4; ++s) {
                    const int e = tid + 512 * s;
                    const int t = wb2 + e;
                    nxt[s] = (e < 1539 && t < T_) ? xb[t] : 0.f;
                }
            }
            run_super(bhp, Adl, sw, lps, A2p, 2 * wave, wb, w << 4,
                      cml, ivv, a0, q, cl);
            #pragma unroll
            for (int s = 0; s < 4; ++s) cur[s] = nxt[s];
        }
    }
    __syncthreads();   // cml complete block-wide

    // ---- initial rm winner: 16 rows -> 1 u64 ----
    {
        #pragma unroll
        for (int rr = 0; rr < 2; ++rr) {
            const int rl = wave * 2 + rr;
            const u64* p = cml + (rl << 8);
            u64 m = umax64(umax64(p[lane], p[lane + 64]),
                           umax64(p[lane + 128], p[lane + 192]));
            #pragma unroll
            for (int o = 32; o > 0; o >>= 1) m = umax64(m, shfl_down_u64(m, o));
            if (lane == 0) red16[rl] = m;
        }
        __syncthreads();
        if (wave == 0) {
            u64 wv = (lane < 16) ? red16[lane] : 0ull;
            #pragma unroll
            for (int o = 8; o > 0; o >>= 1) wv = umax64(wv, shfl_xor_u64(wv, o));
            if (lane == 0) st_au64(&rmW[b * 32 + ag], wv);
        }
    }
    unsigned int gen = 1;
    b_barrier(slots, ag, gen); ++gen;

    for (int it = 0; it < NIT_; ++it) {
        // ---- phase A: global argmax from 32 block winners ----
        const u64* rwp = rmW + ((it & 1) << 8) + b * 32;
        u64 am = ld_au64(&rwp[lane & 31]);
        #pragma unroll
        for (int o = 16; o > 0; o >>= 1) am = umax64(am, shfl_xor_u64(am, o));
        const unsigned int enc = (unsigned int)(am >> 32);
        const unsigned int flat = ~(unsigned int)am;
        const int asel = (int)((flat >> 14) & (NA_ - 1));
        const int tsel = (int)(flat & (T_ - 1));
        const float v = decf(enc);
        if (tid == 0) { selAL[it] = asel; selTL[it] = tsel; selVL[it] = v; }
        if (ag == 0 && tid == 0) {
            selA[it * B_ + b] = asel;
            selT[it * B_ + b] = tsel;
            selV[it * B_ + b] = v;
        }
        if (it == NIT_ - 1) break;   // B-E would only feed a nonexistent iter
        const int L = min(A_, (T_ - 1) - tsel);   // reference truncation quirk
        const float vv = v * inv[asel];

        const float* xrPrev = (it == 0) ? x : ((it & 1) ? xrB : xrA);
        float*       xrNext = (it & 1) ? xrA : xrB;

        // ---- phase C loads hoisted (T14): issue before phase B ----
        int ab = 0, nch = 0, NS = 0;
        float cbuf[4];
        if (L > 0) {
            const int tbeg = max(0, tsel - (A_ - 1));
            const int tend = tsel + L;               // <= 16383
            ab = tbeg & ~63;
            const int ae = (tend + 63) & ~63;        // <= T_
            const int W = ae - ab;                   // <= 1088
            nch = W >> 6;                            // <= 17
            NS = W + 512;                            // <= 1600
            #pragma unroll
            for (int s = 0; s < 4; ++s) {
                const int e = tid + 512 * s;
                const int t = ab + e;
                cbuf[s] = (e < NS + 3 && t < T_) ? ld_af(&xrPrev[b * T_ + t]) : 0.f;
            }
        }

        // ---- phase B: xr ping-pong slice [ag*512, +512) (agent ld/st) ----
        {
            int t = ag * 512 + tid;
            float xv = ld_af(&xrPrev[b * T_ + t]);
            int o = t - tsel;
            if (L > 0 && o >= 0 && o < L) xv = fmaf(-vv, d[asel * A_ + o], xv);
            st_af(&xrNext[b * T_ + t], xv);
        }

        if (L > 0) {
            // ---- phase C: patch+convert from registers; hw dup 4-shift + lp shorts ----
            #pragma unroll
            for (int s = 0; s < 4; ++s) {
                const int e = tid + 512 * s;
                if (e < NS + 3) {
                    float xv = cbuf[s];
                    int o = (ab + e) - tsel;
                    if (o >= 0 && o < L) xv = fmaf(-vv, d[asel * A_ + o], xv);
                    unsigned int pw = packhl(xv);
                    unsigned int hword = (pw & 0xffffu) * 0x10001u;
                    #pragma unroll
                    for (int sh = 0; sh < 4; ++sh) {
                        int i = e - sh;
                        if (i >= 0 && i < NS) hw[sh * 1640 + i] = hword;
                    }
                    unsigned short lo = (unsigned short)(pw >> 16);
                    lp0s[e] = lo;
                    if (e > 0) lp1s[e - 1] = lo;
                }
            }
            __syncthreads();

            // ---- phase D: balanced contiguous runs over waves ----
            {
                const int lo = (wave * nch) >> 3;
                const int hi = ((wave + 1) * nch) >> 3;
                int c = lo;
                for (; c + 1 < hi; c += 2)
                    run_super(bhp, Adl, sw, lps, A2p, c, ab, ab >> 6,
                              cml, ivv, a0, q, cl);
                if (c < hi)
                    run_single(bhp, Adl, sw, lps, A2p, c, ab, ab >> 6,
                               cml, ivv, a0, q, cl);
            }
            __syncthreads();   // cml writes visible block-wide
        }

        // ---- phase E: 16 row maxima -> block winner -> rmW ----
        #pragma unroll
        for (int rr = 0; rr < 2; ++rr) {
            const int rl = wave * 2 + rr;
            const u64* p = cml + (rl << 8);
            u64 m = umax64(umax64(p[lane], p[lane + 64]),
                           umax64(p[lane + 128], p[lane + 192]));
            #pragma unroll
            for (int o = 32; o > 0; o >>= 1) m = umax64(m, shfl_down_u64(m, o));
            if (lane == 0) red16[rl] = m;
        }
        __syncthreads();
        if (wave == 0) {
            u64 wv = (lane < 16) ? red16[lane] : 0ull;
            #pragma unroll
            for (int o = 8; o > 0; o >>= 1) wv = umax64(wv, shfl_xor_u64(wv, o));
            if (lane == 0) st_au64(&rmW[(((it + 1) & 1) << 8) + b * 32 + ag], wv);
        }

        b_barrier(slots, ag, gen); ++gen;
    }

    // ---- final reconstruct (folded k_final) from block-local sel history ----
    __syncthreads();   // selAL[31] visible
    {
        const int t = ag * 512 + tid;
        const int gid = b * T_ + t;
        float r = x[gid];
        float rec = 0.f;
        for (int k = 0; k < NIT_; ++k) {       // sequential: reference fp order
            int a  = selAL[k] & (NA_ - 1);
            int ts = selTL[k] & (T_ - 1);
            float vvl = selVL[k] * inv[a];
            int o = t - ts;
            int Lf = min(A_, (T_ - 1) - ts);
            if (o >= 0 && o < Lf) {
                float c = vvl * d[a * A_ + o];
                r -= c;
                rec += c;
            }
        }
        out[gid] = r;
        out[B_ * T_ + gid] = rec;
    }
}

// ================= fallback path (unchanged, proven r3 structure) =================

__global__ __launch_bounds__(512) void k_conv(const float* __restrict__ x,
                                              const unsigned int* __restrict__ dpk,
                                              const float* __restrict__ inv,
                                              u64* __restrict__ cm,
                                              float* __restrict__ xrA) {
    __shared__ uint4 s_hh[4][202];
    __shared__ uint4 s_ll[4][202];
    const int tid = threadIdx.x;
    const int wave = tid >> 6, lane = tid & 63;
    const int cl = lane & 15, q = lane >> 4;
    const int wb = blockIdx.x * 256;
    const int gb = blockIdx.z;

    unsigned int* hw = (unsigned int*)s_hh;
    unsigned int* lw = (unsigned int*)s_ll;
    for (int e = tid; e < 776; e += 512) {
        int t = wb + e;
        float xv = (t < T_) ? x[gb * T_ + t] : 0.f;
        if (blockIdx.y == 0 && e < 256) xrA[gb * T_ + wb + e] = xv;
        unsigned int pw = packhl(xv);
        unsigned int hword = (pw & 0xffffu) * 0x10001u;
        unsigned int lword = (pw >> 16) * 0x10001u;
        #pragma unroll
        for (int s = 0; s < 4; ++s) {
            int i = e - s;
            if (i >= 0 && i < 772) { hw[s * 808 + i] = hword; lw[s * 808 + i] = lword; }
        }
    }
    __syncthreads();

    const int a_base = blockIdx.y * 128 + (wave & 1) * 64;
    const int t0l = (wave >> 1) * 64;
    const unsigned int* Ap[4];
    #pragma unroll
    for (int at = 0; at < 4; ++at)
        Ap[at] = dpk + ((a_base + 16 * at + cl) << 9) + 4 * q;
    const uint4* bhp = &s_hh[cl & 3][(t0l >> 2) + (cl >> 2) + q];
    const uint4* blp = &s_ll[cl & 3][(t0l >> 2) + (cl >> 2) + q];

    f32x4 acc[4][4];
    const f32x4 zero = {0.f, 0.f, 0.f, 0.f};
    #pragma unroll
    for (int at = 0; at < 4; ++at)
        #pragma unroll
        for (int tt = 0; tt < 4; ++tt) acc[at][tt] = zero;

    for (int j0 = 0; j0 < A_; j0 += 16) {
        Frag Af[4], bh[4], bl[4];
        #pragma unroll
        for (int at = 0; at < 4; ++at) Af[at].u = *(const uint4*)(Ap[at] + j0);
        #pragma unroll
        for (int tt = 0; tt < 4; ++tt) {
            bh[tt].u = bhp[4 * tt + (j0 >> 2)];
            bl[tt].u = blp[4 * tt + (j0 >> 2)];
        }
        #pragma unroll
        for (int tt = 0; tt < 4; ++tt)
            #pragma unroll
            for (int at = 0; at < 4; ++at)
                acc[at][tt] = MFMA16(Af[at].f, bh[tt].f, acc[at][tt]);
        #pragma unroll
        for (int tt = 0; tt < 4; ++tt)
            #pragma unroll
            for (int at = 0; at < 4; ++at)
                acc[at][tt] = MFMA16(Af[at].f, bl[tt].f, acc[at][tt]);
    }

    const int t0 = wb + t0l;
    const int ch = t0 >> 6;
    #pragma unroll
    for (int at = 0; at < 4; ++at) {
        #pragma unroll
        for (int r = 0; r < 4; ++r) {
            const int atom = a_base + 16 * at + 4 * q + r;
            const float iv = inv[atom];
            u64 m = 0ull;
            #pragma unroll
            for (int tt = 0; tt < 4; ++tt) {
                int t = t0 + 16 * tt + cl;
                m = umax64(m, enc64(acc[at][tt][r] * iv, (unsigned int)(atom * T_ + t)));
            }
            m = umax64(m, shfl_xor_u64(m, 1));
            m = umax64(m, shfl_xor_u64(m, 2));
            m = umax64(m, shfl_xor_u64(m, 4));
            m = umax64(m, shfl_xor_u64(m, 8));
            if (cl == 0)
                cm[((size_t)(gb * NA_ + atom) << 8) + ch] = m;
        }
    }
}

__global__ __launch_bounds__(256) void k_tables(const u64* __restrict__ cm, u64* __restrict__ rm) {
    const int row = blockIdx.x * 4 + (threadIdx.x >> 6);
    const int lane = threadIdx.x & 63;
    const u64* p = cm + ((size_t)row << 8);
    u64 m = 0ull;
    #pragma unroll
    for (int k = 0; k < 4; ++k) m = umax64(m, p[lane + 64 * k]);
    #pragma unroll
    for (int o = 32; o > 0; o >>= 1) m = umax64(m, shfl_down_u64(m, o));
    if (lane == 0) rm[row] = m;
}

__global__ __launch_bounds__(512) void k_it(const float* __restrict__ xrPrev,
                                            float* __restrict__ xrNext,
                                            const float* __restrict__ d,
                                            const float* __restrict__ inv,
                                            const unsigned int* __restrict__ dpk,
                                            u64* __restrict__ cm,
                                            const u64* __restrict__ rmPrev,
                                            u64* __restrict__ rmNext,
                                            int* __restrict__ selA,
                                            int* __restrict__ selT,
                                            float* __restrict__ selV,
                                            int it) {
    __shared__ u64 red8[8];
    __shared__ uint4 s_hh[4][410];
    __shared__ uint4 s_ll[4][410];
    __shared__ uint4 dl4[16 * 128];
    const int ag = blockIdx.x, b = blockIdx.y, tid = threadIdx.x;
    const int wave = tid >> 6, lane = tid & 63;
    const int cl = lane & 15, q = lane >> 4;
    const int a0 = ag * 16;

    {
        const uint4* gsrc = (const uint4*)(dpk + (a0 << 9));
        #pragma unroll
        for (int s = 0; s < 4; ++s) {
            int i = tid + 512 * s;
            int row = i >> 7, c4 = i & 127;
            dl4[(row << 7) | (c4 ^ (row & 7))] = gsrc[i];
        }
    }

    const u64* rp = rmPrev + b * NA_;
    u64 am = rp[tid];
    #pragma unroll
    for (int o = 32; o > 0; o >>= 1) am = umax64(am, shfl_xor_u64(am, o));
    if (lane == 0) red8[wave] = am;
    __syncthreads();
    u64 win = red8[0];
    #pragma unroll
    for (int w2 = 1; w2 < 8; ++w2) win = umax64(win, red8[w2]);
    const unsigned int enc = (unsigned int)(win >> 32);
    const unsigned int flat = ~(unsigned int)win;
    const int asel = (int)((flat >> 14) & (NA_ - 1));
    const int tsel = (int)(flat & (T_ - 1));
    const float v = decf(enc);
    if (ag == 0 && tid == 0) {
        selA[it * B_ + b] = asel;
        selT[it * B_ + b] = tsel;
        selV[it * B_ + b] = v;
    }
    const int L = min(A_, (T_ - 1) - tsel);
    const float vv = v * inv[asel];

    {
        int t = ag * 512 + tid;
        float xv = xrPrev[b * T_ + t];
        int o = t - tsel;
        if (L > 0 && o >= 0 && o < L) xv = fmaf(-vv, d[asel * A_ + o], xv);
        xrNext[b * T_ + t] = xv;
    }

    if (L > 0) {
        const int tbeg = max(0, tsel - (A_ - 1));
        const int tend = tsel + L;
        const int ab = tbeg & ~63;
        const int ae = (tend + 63) & ~63;
        const int W = ae - ab;
        const int nch = W >> 6;
        const int NS = W + 512;

        unsigned int* hw = (unsigned int*)s_hh;
        unsigned int* lw = (unsigned int*)s_ll;
        for (int e = tid; e < NS + 3; e += 512) {
            int t = ab + e;
            float xv = (t < T_) ? xrPrev[b * T_ + t] : 0.f;
            int o = t - tsel;
            if (o >= 0 && o < L) xv = fmaf(-vv, d[asel * A_ + o], xv);
            unsigned int pw = packhl(xv);
            unsigned int hword = (pw & 0xffffu) * 0x10001u;
            unsigned int lword = (pw >> 16) * 0x10001u;
            #pragma unroll
            for (int s = 0; s < 4; ++s) {
                int i = e - s;
                if (i >= 0 && i < NS) { hw[s * 1640 + i] = hword; lw[s * 1640 + i] = lword; }
            }
        }
        __syncthreads();

        const uint4* Adl = dl4 + (cl << 7);
        const int sw = cl & 7;
        float ivv[4];
        #pragma unroll
        for (int r = 0; r < 4; ++r) ivv[r] = inv[a0 + 4 * q + r];
        const uint4* bhp = &s_hh[cl & 3][(cl >> 2) + q];
        const uint4* blp = &s_ll[cl & 3][(cl >> 2) + q];

        for (int c = wave; c < nch; c += 8) {
            f32x4 acc[4];
            const f32x4 zero = {0.f, 0.f, 0.f, 0.f};
            #pragma unroll
            for (int tt = 0; tt < 4; ++tt) acc[tt] = zero;

            Frag bh[4], bl[4];
            #pragma unroll
            for (int pp = 0; pp < 4; ++pp) {
                bh[pp].u = bhp[16 * c + 4 * pp];
                bl[pp].u = blp[16 * c + 4 * pp];
            }
            for (int j0 = 0; j0 < A_; j0 += 64) {
                #pragma unroll
                for (int u = 0; u < 4; ++u) {
                    const int jj = j0 + 16 * u;
                    Frag Af;
                    Af.u = Adl[(q + (jj >> 2)) ^ sw];
                    #pragma unroll
                    for (int tt = 0; tt < 4; ++tt)
                        acc[tt] = MFMA16(Af.f, bh[(u + tt) & 3].f, acc[tt]);
                    #pragma unroll
                    for (int tt = 0; tt < 4; ++tt)
                        acc[tt] = MFMA16(Af.f, bl[(u + tt) & 3].f, acc[tt]);
                    bh[u].u = bhp[16 * c + (jj >> 2) + 16];
                    bl[u].u = blp[16 * c + (jj >> 2) + 16];
                }
            }
            #pragma unroll
            for (int r = 0; r < 4; ++r) {
                const int atom = a0 + 4 * q + r;
                u64 mm = 0ull;
                #pragma unroll
                for (int tt = 0; tt < 4; ++tt) {
                    int t = ab + 64 * c + 16 * tt + cl;
                    mm = umax64(mm, enc64(acc[tt][r] * ivv[r], (unsigned int)(atom * T_ + t)));
                }
                mm = umax64(mm, shfl_xor_u64(mm, 1));
                mm = umax64(mm, shfl_xor_u64(mm, 2));
                mm = umax64(mm, shfl_xor_u64(mm, 4));
                mm = umax64(mm, shfl_xor_u64(mm, 8));
                if (cl == 0)
                    cm[((size_t)(b * NA_ + atom) << 8) + (ab >> 6) + c] = mm;
            }
        }
        __syncthreads();
    }

    #pragma unroll
    for (int rr = 0; rr < 2; ++rr) {
        const int row = a0 + wave * 2 + rr;
        const u64* p = cm + ((size_t)(b * NA_ + row) << 8);
        u64 m = umax64(umax64(p[lane], p[lane + 64]),
                       umax64(p[lane + 128], p[lane + 192]));
        #pragma unroll
        for (int o = 32; o > 0; o >>= 1) m = umax64(m, shfl_down_u64(m, o));
        if (lane == 0) rmNext[b * NA_ + row] = m;
    }
}

__global__ void s_init(const float* __restrict__ x, float* __restrict__ xr,
                       u64* __restrict__ cand) {
    int i = blockIdx.x * 256 + threadIdx.x;
    if (i < B_ * T_) xr[i] = x[i];
    if (i < B_) cand[i] = 0ull;
}
__global__ __launch_bounds__(256) void s_scan(const float* __restrict__ xr,
                                              const float* __restrict__ d,
                                              const float* __restrict__ inv,
                                              u64* __restrict__ cand) {
    __shared__ float dLs[A_];
    __shared__ u64 redU[256];
    const int aB = blockIdx.x, b = blockIdx.y, tid = threadIdx.x;
    const float iv = inv[aB];
    for (int i = tid; i < A_; i += 256) dLs[i] = d[aB * A_ + i] * iv;
    __syncthreads();
    const float* xb = xr + b * T_;
    u64 best = 0ull;
    for (int t = tid; t < T_; t += 256) {
        float acc = 0.f;
        int lim = min(A_, T_ - t);
        for (int i = 0; i < lim; ++i) acc = fmaf(dLs[i], xb[t + i], acc);
        best = umax64(best, enc64(acc, (unsigned int)(aB * T_ + t)));
    }
    redU[tid] = best;
    __syncthreads();
    for (int s = 128; s > 0; s >>= 1) {
        if (tid < s) redU[tid] = umax64(redU[tid], redU[tid + s]);
        __syncthreads();
    }
    if (tid == 0) atomicMax(&cand[b], redU[0]);
}
__global__ void s_apply(float* __restrict__ xr, const float* __restrict__ d,
                        const float* __restrict__ inv, u64* __restrict__ cand,
                        int* selA, int* selT, float* selV, int it) {
    const int b = blockIdx.x, tid = threadIdx.x;
    u64 win = cand[b];
    unsigned int enc = (unsigned int)(win >> 32);
    unsigned int flat = ~(unsigned int)win;
    int a = (int)((flat >> 14) & (NA_ - 1)), t = (int)(flat & (T_ - 1));
    float v = decf(enc);
    if (tid == 0) { selA[it * B_ + b] = a; selT[it * B_ + b] = t; selV[it * B_ + b] = v; }
    float vvl = v * inv[a];
    int L = min(A_, (T_ - 1) - t);
    for (int o = tid; o < L; o += 256) xr[b * T_ + t + o] -= vvl * d[a * A_ + o];
    if (tid == 0) cand[b] = 0ull;
}

__global__ __launch_bounds__(256) void k_final(const float* __restrict__ x,
                                               const float* __restrict__ d,
                                               const int* __restrict__ selA,
                                               const int* __restrict__ selT,
                                               const float* __restrict__ selV,
                                               const float* __restrict__ inv,
                                               float* __restrict__ out) {
    const int gid = blockIdx.x * 256 + threadIdx.x;
    const int b = gid >> 14;
    const int t = gid & (T_ - 1);
    float r = x[gid];
    float rec = 0.f;
    for (int k = 0; k < NIT_; ++k) {           // sequential: reference fp order
        int a  = selA[k * B_ + b] & (NA_ - 1);
        int ts = selT[k * B_ + b] & (T_ - 1);
        float vvl = selV[k * B_ + b] * inv[a];
        int o = t - ts;
        int L = min(A_, (T_ - 1) - ts);
        if (o >= 0 && o < L) {
            float c = vvl * d[a * A_ + o];
            r -= c;
            rec += c;
        }
    }
    out[gid] = r;
    out[B_ * T_ + gid] = rec;
}

extern "C" void kernel_launch(void* const* d_in, const int* in_sizes, int n_in,
                              void* d_out, int out_size, void* d_ws, size_t ws_size,
                              hipStream_t stream) {
    const float* x = (const float*)d_in[0];
    const float* d = (const float*)d_in[1];
    float* out = (float*)d_out;
    float* ws = (float*)d_ws;
    const size_t wsf = ws_size / sizeof(float);

    float* inv  = ws + OFF_INV;
    int*   selA = (int*)(ws + OFF_SELA);
    int*   selT = (int*)(ws + OFF_SELT);
    float* selV = ws + OFF_SELV;

    if (wsf < (size_t)S_NEED) return;   // hopeless

    const bool persistOK = wsf >= (size_t)PERS_NEED;
    unsigned int* bar = persistOK ? (unsigned int*)(ws + OFF_BAR) : (unsigned int*)0;

    k_inv<<<dim3(NA_), dim3(64), 0, stream>>>(d, inv, bar);

    if (wsf >= (size_t)MAIN_NEED) {
        u64* cm  = (u64*)(ws + OFF_CM);
        u64* rmA = (u64*)(ws + OFF_RMA);
        u64* rmB = (u64*)(ws + OFF_RMB);
        float* xrA = ws + OFF_XRA;
        float* xrB = ws + OFF_XRB;
        unsigned int* dpk = (unsigned int*)(ws + OFF_DPK);

        if (persistOK) {
            u64* rmW = (u64*)(ws + OFF_RMA);    // u64[2][256]
            k_persist<<<dim3(NA_ / 16, B_), dim3(512), 0, stream>>>(x, xrA, xrB, d, inv,
                                                                    rmW, selA, selT, selV,
                                                                    bar, out);
            return;   // out fully written by k_persist
        }

        k_split_d<<<dim3(NA_ * A_ / 256), dim3(256), 0, stream>>>(d, dpk);
        k_conv<<<dim3(T_ / 256, NA_ / 128, B_), dim3(512), 0, stream>>>(x, dpk, inv, cm, xrA);
        k_tables<<<dim3(B_ * NA_ / 4), dim3(256), 0, stream>>>(cm, rmA);
        for (int it = 0; it < NIT_; ++it) {
            const float* xp = (it & 1) ? xrB : xrA;
            float*       xn = (it & 1) ? xrA : xrB;
            const u64*   ro = (it & 1) ? rmB : rmA;
            u64*         rn = (it & 1) ? rmA : rmB;
            k_it<<<dim3(NA_ / 16, B_), dim3(512), 0, stream>>>(xp, xn, d, inv, dpk,
                                                               cm, ro, rn,
                                                               selA, selT, selV, it);
        }
    } else {
        float* xr = ws + OFF_SXR;
        u64* cand = (u64*)(ws + OFF_SCAND);
        s_init<<<dim3((B_ * T_ + 255) / 256), dim3(256), 0, stream>>>(x, xr, cand);
        for (int it = 0; it < NIT_; ++it) {
            s_scan<<<dim3(NA_, B_), dim3(256), 0, stream>>>(xr, d, inv, cand);
            s_apply<<<dim3(B_), dim3(256), 0, stream>>>(xr, d, inv, cand, selA, selT, selV, it);
        }
    }

    k_final<<<dim3(B_ * T_ / 256), dim3(256), 0, stream>>>(x, d, selA, selT, selV, inv, out);
}

// Round 12
// 699.031 us; speedup vs baseline: 1.1605x; 1.0106x over previous
//
#include <hip/hip_runtime.h>
#include <cstdint>

#define B_    8
#define T_    16384
#define NA_   512
#define A_    512
#define NIT_  32
#define EPSV  1e-8f

typedef unsigned long long u64;
typedef __attribute__((ext_vector_type(8))) short bf16x8;
typedef __attribute__((ext_vector_type(4))) float f32x4;

union Frag { uint4 u; bf16x8 f; };

#define MFMA16(a, b, c) __builtin_amdgcn_mfma_f32_16x16x32_bf16((a), (b), (c), 0, 0, 0)

// ws float-offset layout
#define OFF_INV   0
#define OFF_SELA  512
#define OFF_SELT  768
#define OFF_SELV  1024
#define OFF_CM    1280        // u64[8*512*256] (fallback path only)
#define OFF_RMA   2098432     // persistent: rmW u64[2][256]; fallback: rm u64[4096]
#define OFF_RMB   2106624     // u64[4096] (fallback)
#define OFF_XRA   2114816     // f32[8*16384]
#define OFF_XRB   2245888     // f32[8*16384]
#define OFF_DPK   2376960     // u32[512*512]  (fallback path only)
#define MAIN_NEED 2639104     // launch-loop requirement
#define OFF_BAR   2639104     // u32 gen-slots: 8 batches x 32 blocks x 16-dword stride
#define PERS_NEED (OFF_BAR + 4096)
// compact fallback layout
#define OFF_SXR   OFF_CM
#define OFF_SCAND (OFF_CM + 131072)
#define S_NEED    (OFF_SCAND + 16)

__device__ __forceinline__ unsigned int encf(float f) {
    unsigned int u = __float_as_uint(f);
    return (u & 0x80000000u) ? ~u : (u | 0x80000000u);
}
__device__ __forceinline__ float decf(unsigned int e) {
    unsigned int u = (e & 0x80000000u) ? (e & 0x7fffffffu) : ~e;
    return __uint_as_float(u);
}
__device__ __forceinline__ u64 umax64(u64 a, u64 b) { return a > b ? a : b; }
__device__ __forceinline__ u64 enc64(float v, unsigned int flat) {
    return (((u64)encf(v)) << 32) | (unsigned int)~flat;
}
__device__ __forceinline__ u64 shfl_xor_u64(u64 v, int mask) {
    unsigned int lo = (unsigned int)v, hi = (unsigned int)(v >> 32);
    lo = __shfl_xor(lo, mask, 64);
    hi = __shfl_xor(hi, mask, 64);
    return (((u64)hi) << 32) | lo;
}
__device__ __forceinline__ u64 shfl_down_u64(u64 v, int off) {
    unsigned int lo = (unsigned int)v, hi = (unsigned int)(v >> 32);
    lo = __shfl_down(lo, off, 64);
    hi = __shfl_down(hi, off, 64);
    return (((u64)hi) << 32) | lo;
}
// bf16 round-to-nearest-even from fp32
__device__ __forceinline__ unsigned short f2bf(float v) {
    unsigned int u = __float_as_uint(v);
    return (unsigned short)((u + 0x7fffu + ((u >> 16) & 1u)) >> 16);
}
// float -> (hi-bf16 | lo-bf16<<16), bit-identical to k_split_d
__device__ __forceinline__ unsigned int packhl(float v) {
    unsigned short hb = f2bf(v);
    unsigned short lb = f2bf(v - __uint_as_float((unsigned int)hb << 16));
    return (unsigned int)hb | ((unsigned int)lb << 16);
}

// agent-scope (cross-XCD coherent, L2-bypassing) data ops (r5-proven).
__device__ __forceinline__ float ld_af(const float* p) {
    return __hip_atomic_load(p, __ATOMIC_RELAXED, __HIP_MEMORY_SCOPE_AGENT);
}
__device__ __forceinline__ void st_af(float* p, float v) {
    __hip_atomic_store(p, v, __ATOMIC_RELAXED, __HIP_MEMORY_SCOPE_AGENT);
}
__device__ __forceinline__ u64 ld_au64(const u64* p) {
    return __hip_atomic_load(p, __ATOMIC_RELAXED, __HIP_MEMORY_SCOPE_AGENT);
}
__device__ __forceinline__ void st_au64(u64* p, u64 v) {
    __hip_atomic_store(p, v, __ATOMIC_RELAXED, __HIP_MEMORY_SCOPE_AGENT);
}

// per-b 32-block distributed-flag barrier (r10-proven).
__device__ __forceinline__ void b_barrier(unsigned int* slots, int ag, unsigned int gen) {
    __syncthreads();
    const int tid = threadIdx.x;
    if (tid == 0)
        __hip_atomic_store(&slots[ag << 4], gen, __ATOMIC_RELAXED, __HIP_MEMORY_SCOPE_AGENT);
    if (tid < 64) {
        const unsigned int* sp = &slots[(tid & 31) << 4];
        int spins = 0;
        while (__hip_atomic_load(sp, __ATOMIC_RELAXED, __HIP_MEMORY_SCOPE_AGENT) < gen) {
            __builtin_amdgcn_s_sleep(1);
            if (++spins > (1 << 20)) break;   // safety valve
        }
    }
    __syncthreads();
    asm volatile("" ::: "memory");
}

// lp fragment load: 4 x b32 (per-lane parity defeats 16B alignment).
__device__ __forceinline__ uint4 lp4(const unsigned int* lps, int w) {
    uint4 r;
    r.x = lps[w]; r.y = lps[w + 1]; r.z = lps[w + 2]; r.w = lps[w + 3];
    return r;
}

// ---------------------------------------------------------------------------
// 3-term hi/lo scheme (r11): conv = (hi_d+lo_d)*hi_x  +  hi_d*lo_x
// (lo_d*lo_x dropped: ~2^-16 relative, below the bf16 rounding floor).
//   P1 (32 K-steps): A = dl4 (hi_d|lo_d interleaved), B = s_hh (hi_x dup).
//   P2 (16 K-steps): A = ah4 (hi_d pairs, dense),     B = lp (lo_x pairs).
// P2 rotation: slot (g+2*j2)&DEPTH-1; 2 refills/step feed step j2+1 (r7
// lesson: refills are consumed by later steps; ONLY the final step's refills
// are dead -> in-bounds junk, never consumed). j2 unrolled so all slot
// indices constant-fold (rule #20).
// ---------------------------------------------------------------------------

// one 128-t super-chunk (chunks c0, c0+1): 8 output t-tiles.
// P1: 256 MFMA; P2: 128 MFMA.
__device__ __forceinline__ void run_super(const uint4* bhp,
                                          const uint4* Adl, int sw,
                                          const unsigned int* lps,
                                          const uint4* A2p,
                                          int c0, int tbase, int chbase,
                                          u64* cml, const float* ivv,
                                          int a0, int q, int cl) {
    const int base = c0 << 4;
    f32x4 acc[8];
    const f32x4 zero = {0.f, 0.f, 0.f, 0.f};
    #pragma unroll
    for (int g = 0; g < 8; ++g) acc[g] = zero;

    // ---- P1: (hi_d,lo_d) x dup(hi_x), 32 steps, 8-deep rotating file ----
    {
        Frag bh[8];
        #pragma unroll
        for (int pp = 0; pp < 8; ++pp) bh[pp].u = bhp[base + 4 * pp];
        for (int js0 = 0; js0 < 32; js0 += 8) {
            #pragma unroll
            for (int ju = 0; ju < 8; ++ju) {
                const int js = js0 + ju;
                Frag Af;
                Af.u = Adl[(q + 4 * js) ^ sw];
                #pragma unroll
                for (int g = 0; g < 8; ++g)
                    acc[g] = MFMA16(Af.f, bh[(g + ju) & 7].f, acc[g]);
                bh[ju].u = bhp[base + 4 * (js + 8)];   // in-bounds (<=396<410)
            }
        }
    }
    // ---- P2: hi_d pairs x lo_x pairs, 16 steps, 8-deep file, 2 refills ----
    {
        const int bb = 32 * c0 + 4 * q + (cl >> 1);
        Frag b2[8];
        #pragma unroll
        for (int m = 0; m < 8; ++m) b2[m].u = lp4(lps, bb + 8 * m);
        for (int j2b = 0; j2b < 4; ++j2b) {
            #pragma unroll
            for (int j2u = 0; j2u < 4; ++j2u) {
                const int j2 = 4 * j2b + j2u;
                Frag A2;
                A2.u = A2p[(4 * j2 + q) ^ sw];
                #pragma unroll
                for (int g = 0; g < 8; ++g)
                    acc[g] = MFMA16(A2.f, b2[(g + 2 * j2u) & 7].f, acc[g]);
                b2[(2 * j2u) & 7].u     = lp4(lps, bb + 8 * (2 * j2 + 8));
                b2[(2 * j2u + 1) & 7].u = lp4(lps, bb + 8 * (2 * j2 + 9));
            }
        }
    }
    #pragma unroll
    for (int r = 0; r < 4; ++r) {
        const int atom4 = 4 * q + r;
        const int atom = a0 + atom4;
        u64 m0 = 0ull, m1 = 0ull;
        #pragma unroll
        for (int g = 0; g < 4; ++g) {
            int t = tbase + 64 * c0 + 16 * g + cl;
            m0 = umax64(m0, enc64(acc[g][r] * ivv[r], (unsigned int)(atom * T_ + t)));
        }
        #pragma unroll
        for (int g = 4; g < 8; ++g) {
            int t = tbase + 64 * c0 + 16 * g + cl;
            m1 = umax64(m1, enc64(acc[g][r] * ivv[r], (unsigned int)(atom * T_ + t)));
        }
        m0 = umax64(m0, shfl_xor_u64(m0, 1));
        m0 = umax64(m0, shfl_xor_u64(m0, 2));
        m0 = umax64(m0, shfl_xor_u64(m0, 4));
        m0 = umax64(m0, shfl_xor_u64(m0, 8));
        m1 = umax64(m1, shfl_xor_u64(m1, 1));
        m1 = umax64(m1, shfl_xor_u64(m1, 2));
        m1 = umax64(m1, shfl_xor_u64(m1, 4));
        m1 = umax64(m1, shfl_xor_u64(m1, 8));
        if (cl == 0) {
            cml[(atom4 << 8) + chbase + c0] = m0;
            cml[(atom4 << 8) + chbase + c0 + 1] = m1;
        }
    }
}

// one 64-t chunk: 4 output t-tiles. P1: 128 MFMA; P2: 64 MFMA.
__device__ __forceinline__ void run_single(const uint4* bhp,
                                           const uint4* Adl, int sw,
                                           const unsigned int* lps,
                                           const uint4* A2p,
                                           int c, int tbase, int chbase,
                                           u64* cml, const float* ivv,
                                           int a0, int q, int cl) {
    const int base = c << 4;
    f32x4 acc[4];
    const f32x4 zero = {0.f, 0.f, 0.f, 0.f};
    #pragma unroll
    for (int g = 0; g < 4; ++g) acc[g] = zero;

    // ---- P1: 4-deep rotating file ----
    {
        Frag bh[4];
        #pragma unroll
        for (int pp = 0; pp < 4; ++pp) bh[pp].u = bhp[base + 4 * pp];
        for (int js0 = 0; js0 < 32; js0 += 4) {
            #pragma unroll
            for (int ju = 0; ju < 4; ++ju) {
                const int js = js0 + ju;
                Frag Af;
                Af.u = Adl[(q + 4 * js) ^ sw];
                #pragma unroll
                for (int g = 0; g < 4; ++g)
                    acc[g] = MFMA16(Af.f, bh[(g + ju) & 3].f, acc[g]);
                bh[ju].u = bhp[base + 4 * (js + 4)];
            }
        }
    }
    // ---- P2: 16 steps, 4-deep file, 2 refills/step ----
    {
        const int bb = 32 * c + 4 * q + (cl >> 1);
        Frag b2[4];
        #pragma unroll
        for (int m = 0; m < 4; ++m) b2[m].u = lp4(lps, bb + 8 * m);
        for (int j2b = 0; j2b < 8; ++j2b) {
            #pragma unroll
            for (int j2u = 0; j2u < 2; ++j2u) {
                const int j2 = 2 * j2b + j2u;
                Frag A2;
                A2.u = A2p[(4 * j2 + q) ^ sw];
                #pragma unroll
                for (int g = 0; g < 4; ++g)
                    acc[g] = MFMA16(A2.f, b2[(g + 2 * j2u) & 3].f, acc[g]);
                b2[(2 * j2u) & 3].u     = lp4(lps, bb + 8 * (2 * j2 + 4));
                b2[(2 * j2u + 1) & 3].u = lp4(lps, bb + 8 * (2 * j2 + 5));
            }
        }
    }
    #pragma unroll
    for (int r = 0; r < 4; ++r) {
        const int atom4 = 4 * q + r;
        const int atom = a0 + atom4;
        u64 m0 = 0ull;
        #pragma unroll
        for (int g = 0; g < 4; ++g) {
            int t = tbase + 64 * c + 16 * g + cl;
            m0 = umax64(m0, enc64(acc[g][r] * ivv[r], (unsigned int)(atom * T_ + t)));
        }
        m0 = umax64(m0, shfl_xor_u64(m0, 1));
        m0 = umax64(m0, shfl_xor_u64(m0, 2));
        m0 = umax64(m0, shfl_xor_u64(m0, 4));
        m0 = umax64(m0, shfl_xor_u64(m0, 8));
        if (cl == 0)
            cml[(atom4 << 8) + chbase + c] = m0;
    }
}

// ---------------- inv[a] = 1/(||d_a||+eps); also zero barrier slots ----------------
__global__ __launch_bounds__(64) void k_inv(const float* __restrict__ d, float* __restrict__ inv,
                                            unsigned int* __restrict__ bar) {
    const int a = blockIdx.x, lane = threadIdx.x;
    if (bar && a == 0) {
        for (int i = lane; i < 4096; i += 64) bar[i] = 0u;
    }
    const float* row = d + a * A_;
    float s = 0.f;
    for (int i = lane; i < A_; i += 64) { float v = row[i]; s = fmaf(v, v, s); }
    #pragma unroll
    for (int o = 32; o > 0; o >>= 1) s += __shfl_down(s, o, 64);
    if (lane == 0) inv[a] = 1.0f / (sqrtf(s) + EPSV);
}

// ---------------- d -> packed (hi | lo<<16) (fallback path only) ----------------
__global__ __launch_bounds__(256) void k_split_d(const float* __restrict__ d,
                                                 unsigned int* __restrict__ dpk) {
    int id = blockIdx.x * 256 + threadIdx.x;           // 262144
    dpk[id] = packhl(d[id]);
}

// ---------------- persistent everything-kernel ----------------
// grid (32 ag, 8 b) = 256 blocks; ~145 KB LDS forces 1 block/CU, grid == CU
// count -> co-resident -> software barrier safe (r5-proven).
// r12: pass -1 staging double-buffered (s_hh/lp x2). Per window: issue w+1
// loads (T14) -> run_super(w) on buf[w&1] -> convert+write w+1 into
// buf[(w+1)&1] -> ONE barrier (was 2). Convert overlaps other waves' MFMA
// (different buffer; buf[(w+1)&1]'s next reader is run_super(w+1), after the
// barrier; buf[w&1]'s next writer is window w+1's convert, also after it).
// Iterations use buffer 0 only (argmax dependency precludes pipelining).
__global__ __launch_bounds__(512) void k_persist(const float* __restrict__ x,
                                                 float* __restrict__ xrA,
                                                 float* __restrict__ xrB,
                                                 const float* __restrict__ d,
                                                 const float* __restrict__ inv,
                                                 u64* __restrict__ rmW,
                                                 int* __restrict__ selA,
                                                 int* __restrict__ selT,
                                                 float* __restrict__ selV,
                                                 unsigned int* __restrict__ bar,
                                                 float* __restrict__ out) {
    __shared__ u64 red16[16];
    __shared__ int   selAL[NIT_];
    __shared__ int   selTL[NIT_];
    __shared__ float selVL[NIT_];
    __shared__ uint4 s_hh[2][4][410];      // hi_x dup, 4 shift copies, x2 buffers
    __shared__ unsigned int lp[2][2][816]; // lo_x pairs, even/odd copies, x2 buffers
    __shared__ uint4 ah4[16 * 64];         // hi_d pairs, swizzled (P2 A), 16 KB
    __shared__ uint4 dl4[16 * 128];        // (hi_d|lo_d), swizzled (P1 A), 32 KB
    __shared__ u64  cml[16 * 256];         // block-private cm rows, 32 KB
    const int ag = blockIdx.x, b = blockIdx.y, tid = threadIdx.x;
    const int wave = tid >> 6, lane = tid & 63;
    const int cl = lane & 15, q = lane >> 4;
    const int a0 = ag * 16;
    unsigned int* slots = bar + (b << 9);   // 32 slots x 16-dword stride

    // ---- one-time staging: dl4 (interleaved) + ah4 (hi pairs), both swizzled ----
    {
        const float4* gsrc = (const float4*)(d + (a0 << 9));
        unsigned int* ah32 = (unsigned int*)ah4;
        #pragma unroll
        for (int s = 0; s < 4; ++s) {
            int i = tid + 512 * s;
            int row = i >> 7, c4 = i & 127;
            float4 f = gsrc[i];
            uint4 pk;
            pk.x = packhl(f.x);
            pk.y = packhl(f.y);
            pk.z = packhl(f.z);
            pk.w = packhl(f.w);
            dl4[(row << 7) | (c4 ^ (row & 7))] = pk;
            unsigned int d0 = (pk.x & 0xffffu) | ((pk.y & 0xffffu) << 16);
            unsigned int d1 = (pk.z & 0xffffu) | ((pk.w & 0xffffu) << 16);
            int u = c4 >> 1;
            int l0 = (2 * c4) & 3;
            int abase = (row << 8) + ((u ^ (row & 7)) << 2);
            ah32[abase + l0] = d0;
            ah32[abase + l0 + 1] = d1;
        }
    }

    // ---- hoisted constants ----
    const uint4* Adl = dl4 + (cl << 7);
    const uint4* A2p = ah4 + (cl << 6);
    const int sw = cl & 7;
    const unsigned int* lps0 = &lp[0][cl & 1][0];
    const unsigned int* lps1 = &lp[1][cl & 1][0];
    float ivv[4];
    #pragma unroll
    for (int r = 0; r < 4; ++r) ivv[r] = inv[a0 + 4 * q + r];
    const uint4* bhp0 = &s_hh[0][cl & 3][(cl >> 2) + q];
    const uint4* bhp1 = &s_hh[1][cl & 3][(cl >> 2) + q];
    unsigned int* hw0 = (unsigned int*)s_hh[0];
    unsigned short* lp00s = (unsigned short*)&lp[0][0][0];
    unsigned short* lp01s = (unsigned short*)&lp[0][1][0];

    // ---- pass -1: initial full conv into cml (16 windows x 1024 t, dbuf) ----
    {
        const float* xb = x + b * T_;
        // prologue: stage window 0 into buffer 0
        #pragma unroll
        for (int s = 0; s < 4; ++s) {
            const int e = tid + 512 * s;
            if (e < 1539) {
                unsigned int pw = packhl(xb[e]);        // window 0: t = e < T_
                unsigned int hword = (pw & 0xffffu) * 0x10001u;
                #pragma unroll
                for (int sh = 0; sh < 4; ++sh) {
                    int i = e - sh;
                    if (i >= 0 && i < 1536) hw0[sh * 1640 + i] = hword;
                }
                unsigned short lo = (unsigned short)(pw >> 16);
                lp00s[e] = lo;
                if (e > 0) lp01s[e - 1] = lo;
            }
        }
        __syncthreads();
        float nxt[4];
        for (int w = 0; w < 16; ++w) {
            const int wb = w << 10;
            if (w + 1 < 16) {                // T14: issue next window's loads now
                const int wb2 = (w + 1) << 10;
                #pragma unroll
                for (int s = 0; s < 4; ++s) {
                    const int e = tid + 512 * s;
                    const int t = wb2 + e;
                    nxt[s] = (e < 1539 && t < T_) ? xb[t] : 0.f;
                }
            }
            const uint4* bhp_w = (w & 1) ? bhp1 : bhp0;
            const unsigned int* lps_w = (w & 1) ? lps1 : lps0;
            run_super(bhp_w, Adl, sw, lps_w, A2p, 2 * wave, wb, w << 4,
                      cml, ivv, a0, q, cl);
            if (w + 1 < 16) {                // stage w+1 into the OTHER buffer
                unsigned int* hwN = (unsigned int*)s_hh[(w + 1) & 1];
                unsigned short* lN0 = (unsigned short*)&lp[(w + 1) & 1][0][0];
                unsigned short* lN1 = (unsigned short*)&lp[(w + 1) & 1][1][0];
                #pragma unroll
                for (int s = 0; s < 4; ++s) {
                    const int e = tid + 512 * s;
                    if (e < 1539) {
                        unsigned int pw = packhl(nxt[s]);
                        unsigned int hword = (pw & 0xffffu) * 0x10001u;
                        #pragma unroll
                        for (int sh = 0; sh < 4; ++sh) {
                            int i = e - sh;
                            if (i >= 0 && i < 1536) hwN[sh * 1640 + i] = hword;
                        }
                        unsigned short lo = (unsigned short)(pw >> 16);
                        lN0[e] = lo;
                        if (e > 0) lN1[e - 1] = lo;
                    }
                }
            }
            __syncthreads();
        }
    }
    // cml complete block-wide (last loop barrier covers it)

    // ---- initial rm winner: 16 rows -> 1 u64 ----
    {
        #pragma unroll
        for (int rr = 0; rr < 2; ++rr) {
            const int rl = wave * 2 + rr;
            const u64* p = cml + (rl << 8);
            u64 m = umax64(umax64(p[lane], p[lane + 64]),
                           umax64(p[lane + 128], p[lane + 192]));
            #pragma unroll
            for (int o = 32; o > 0; o >>= 1) m = umax64(m, shfl_down_u64(m, o));
            if (lane == 0) red16[rl] = m;
        }
        __syncthreads();
        if (wave == 0) {
            u64 wv = (lane < 16) ? red16[lane] : 0ull;
            #pragma unroll
            for (int o = 8; o > 0; o >>= 1) wv = umax64(wv, shfl_xor_u64(wv, o));
            if (lane == 0) st_au64(&rmW[b * 32 + ag], wv);
        }
    }
    unsigned int gen = 1;
    b_barrier(slots, ag, gen); ++gen;

    for (int it = 0; it < NIT_; ++it) {
        // ---- phase A: global argmax from 32 block winners ----
        const u64* rwp = rmW + ((it & 1) << 8) + b * 32;
        u64 am = ld_au64(&rwp[lane & 31]);
        #pragma unroll
        for (int o = 16; o > 0; o >>= 1) am = umax64(am, shfl_xor_u64(am, o));
        const unsigned int enc = (unsigned int)(am >> 32);
        const unsigned int flat = ~(unsigned int)am;
        const int asel = (int)((flat >> 14) & (NA_ - 1));
        const int tsel = (int)(flat & (T_ - 1));
        const float v = decf(enc);
        if (tid == 0) { selAL[it] = asel; selTL[it] = tsel; selVL[it] = v; }
        if (ag == 0 && tid == 0) {
            selA[it * B_ + b] = asel;
            selT[it * B_ + b] = tsel;
            selV[it * B_ + b] = v;
        }
        if (it == NIT_ - 1) break;   // B-E would only feed a nonexistent iter
        const int L = min(A_, (T_ - 1) - tsel);   // reference truncation quirk
        const float vv = v * inv[asel];

        const float* xrPrev = (it == 0) ? x : ((it & 1) ? xrB : xrA);
        float*       xrNext = (it & 1) ? xrA : xrB;

        // ---- phase C loads hoisted (T14): issue before phase B ----
        int ab = 0, nch = 0, NS = 0;
        float cbuf[4];
        if (L > 0) {
            const int tbeg = max(0, tsel - (A_ - 1));
            const int tend = tsel + L;               // <= 16383
            ab = tbeg & ~63;
            const int ae = (tend + 63) & ~63;        // <= T_
            const int W = ae - ab;                   // <= 1088
            nch = W >> 6;                            // <= 17
            NS = W + 512;                            // <= 1600
            #pragma unroll
            for (int s = 0; s < 4; ++s) {
                const int e = tid + 512 * s;
                const int t = ab + e;
                cbuf[s] = (e < NS + 3 && t < T_) ? ld_af(&xrPrev[b * T_ + t]) : 0.f;
            }
        }

        // ---- phase B: xr ping-pong slice [ag*512, +512) (agent ld/st) ----
        {
            int t = ag * 512 + tid;
            float xv = ld_af(&xrPrev[b * T_ + t]);
            int o = t - tsel;
            if (L > 0 && o >= 0 && o < L) xv = fmaf(-vv, d[asel * A_ + o], xv);
            st_af(&xrNext[b * T_ + t], xv);
        }

        if (L > 0) {
            // ---- phase C: patch+convert from registers; hw dup 4-shift + lp shorts ----
            #pragma unroll
            for (int s = 0; s < 4; ++s) {
                const int e = tid + 512 * s;
                if (e < NS + 3) {
                    float xv = cbuf[s];
                    int o = (ab + e) - tsel;
                    if (o >= 0 && o < L) xv = fmaf(-vv, d[asel * A_ + o], xv);
                    unsigned int pw = packhl(xv);
                    unsigned int hword = (pw & 0xffffu) * 0x10001u;
                    #pragma unroll
                    for (int sh = 0; sh < 4; ++sh) {
                        int i = e - sh;
                        if (i >= 0 && i < NS) hw0[sh * 1640 + i] = hword;
                    }
                    unsigned short lo = (unsigned short)(pw >> 16);
                    lp00s[e] = lo;
                    if (e > 0) lp01s[e - 1] = lo;
                }
            }
            __syncthreads();

            // ---- phase D: balanced contiguous runs over waves ----
            {
                const int lo = (wave * nch) >> 3;
                const int hi = ((wave + 1) * nch) >> 3;
                int c = lo;
                for (; c + 1 < hi; c += 2)
                    run_super(bhp0, Adl, sw, lps0, A2p, c, ab, ab >> 6,
                              cml, ivv, a0, q, cl);
                if (c < hi)
                    run_single(bhp0, Adl, sw, lps0, A2p, c, ab, ab >> 6,
                               cml, ivv, a0, q, cl);
            }
            __syncthreads();   // cml writes visible block-wide
        }

        // ---- phase E: 16 row maxima -> block winner -> rmW ----
        #pragma unroll
        for (int rr = 0; rr < 2; ++rr) {
            const int rl = wave * 2 + rr;
            const u64* p = cml + (rl << 8);
            u64 m = umax64(umax64(p[lane], p[lane + 64]),
                           umax64(p[lane + 128], p[lane + 192]));
            #pragma unroll
            for (int o = 32; o > 0; o >>= 1) m = umax64(m, shfl_down_u64(m, o));
            if (lane == 0) red16[rl] = m;
        }
        __syncthreads();
        if (wave == 0) {
            u64 wv = (lane < 16) ? red16[lane] : 0ull;
            #pragma unroll
            for (int o = 8; o > 0; o >>= 1) wv = umax64(wv, shfl_xor_u64(wv, o));
            if (lane == 0) st_au64(&rmW[(((it + 1) & 1) << 8) + b * 32 + ag], wv);
        }

        b_barrier(slots, ag, gen); ++gen;
    }

    // ---- final reconstruct (folded k_final) from block-local sel history ----
    __syncthreads();   // selAL[31] visible
    {
        const int t = ag * 512 + tid;
        const int gid = b * T_ + t;
        float r = x[gid];
        float rec = 0.f;
        for (int k = 0; k < NIT_; ++k) {       // sequential: reference fp order
            int a  = selAL[k] & (NA_ - 1);
            int ts = selTL[k] & (T_ - 1);
            float vvl = selVL[k] * inv[a];
            int o = t - ts;
            int Lf = min(A_, (T_ - 1) - ts);
            if (o >= 0 && o < Lf) {
                float c = vvl * d[a * A_ + o];
                r -= c;
                rec += c;
            }
        }
        out[gid] = r;
        out[B_ * T_ + gid] = rec;
    }
}

// ================= fallback path (unchanged, proven r3 structure) =================

__global__ __launch_bounds__(512) void k_conv(const float* __restrict__ x,
                                              const unsigned int* __restrict__ dpk,
                                              const float* __restrict__ inv,
                                              u64* __restrict__ cm,
                                              float* __restrict__ xrA) {
    __shared__ uint4 s_hh[4][202];
    __shared__ uint4 s_ll[4][202];
    const int tid = threadIdx.x;
    const int wave = tid >> 6, lane = tid & 63;
    const int cl = lane & 15, q = lane >> 4;
    const int wb = blockIdx.x * 256;
    const int gb = blockIdx.z;

    unsigned int* hw = (unsigned int*)s_hh;
    unsigned int* lw = (unsigned int*)s_ll;
    for (int e = tid; e < 776; e += 512) {
        int t = wb + e;
        float xv = (t < T_) ? x[gb * T_ + t] : 0.f;
        if (blockIdx.y == 0 && e < 256) xrA[gb * T_ + wb + e] = xv;
        unsigned int pw = packhl(xv);
        unsigned int hword = (pw & 0xffffu) * 0x10001u;
        unsigned int lword = (pw >> 16) * 0x10001u;
        #pragma unroll
        for (int s = 0; s < 4; ++s) {
            int i = e - s;
            if (i >= 0 && i < 772) { hw[s * 808 + i] = hword; lw[s * 808 + i] = lword; }
        }
    }
    __syncthreads();

    const int a_base = blockIdx.y * 128 + (wave & 1) * 64;
    const int t0l = (wave >> 1) * 64;
    const unsigned int* Ap[4];
    #pragma unroll
    for (int at = 0; at < 4; ++at)
        Ap[at] = dpk + ((a_base + 16 * at + cl) << 9) + 4 * q;
    const uint4* bhp = &s_hh[cl & 3][(t0l >> 2) + (cl >> 2) + q];
    const uint4* blp = &s_ll[cl & 3][(t0l >> 2) + (cl >> 2) + q];

    f32x4 acc[4][4];
    const f32x4 zero = {0.f, 0.f, 0.f, 0.f};
    #pragma unroll
    for (int at = 0; at < 4; ++at)
        #pragma unroll
        for (int tt = 0; tt < 4; ++tt) acc[at][tt] = zero;

    for (int j0 = 0; j0 < A_; j0 += 16) {
        Frag Af[4], bh[4], bl[4];
        #pragma unroll
        for (int at = 0; at < 4; ++at) Af[at].u = *(const uint4*)(Ap[at] + j0);
        #pragma unroll
        for (int tt = 0; tt < 4; ++tt) {
            bh[tt].u = bhp[4 * tt + (j0 >> 2)];
            bl[tt].u = blp[4 * tt + (j0 >> 2)];
        }
        #pragma unroll
        for (int tt = 0; tt < 4; ++tt)
            #pragma unroll
            for (int at = 0; at < 4; ++at)
                acc[at][tt] = MFMA16(Af[at].f, bh[tt].f, acc[at][tt]);
        #pragma unroll
        for (int tt = 0; tt < 4; ++tt)
            #pragma unroll
            for (int at = 0; at < 4; ++at)
                acc[at][tt] = MFMA16(Af[at].f, bl[tt].f, acc[at][tt]);
    }

    const int t0 = wb + t0l;
    const int ch = t0 >> 6;
    #pragma unroll
    for (int at = 0; at < 4; ++at) {
        #pragma unroll
        for (int r = 0; r < 4; ++r) {
            const int atom = a_base + 16 * at + 4 * q + r;
            const float iv = inv[atom];
            u64 m = 0ull;
            #pragma unroll
            for (int tt = 0; tt < 4; ++tt) {
                int t = t0 + 16 * tt + cl;
                m = umax64(m, enc64(acc[at][tt][r] * iv, (unsigned int)(atom * T_ + t)));
            }
            m = umax64(m, shfl_xor_u64(m, 1));
            m = umax64(m, shfl_xor_u64(m, 2));
            m = umax64(m, shfl_xor_u64(m, 4));
            m = umax64(m, shfl_xor_u64(m, 8));
            if (cl == 0)
                cm[((size_t)(gb * NA_ + atom) << 8) + ch] = m;
        }
    }
}

__global__ __launch_bounds__(256) void k_tables(const u64* __restrict__ cm, u64* __restrict__ rm) {
    const int row = blockIdx.x * 4 + (threadIdx.x >> 6);
    const int lane = threadIdx.x & 63;
    const u64* p = cm + ((size_t)row << 8);
    u64 m = 0ull;
    #pragma unroll
    for (int k = 0; k < 4; ++k) m = umax64(m, p[lane + 64 * k]);
    #pragma unroll
    for (int o = 32; o > 0; o >>= 1) m = umax64(m, shfl_down_u64(m, o));
    if (lane == 0) rm[row] = m;
}

__global__ __launch_bounds__(512) void k_it(const float* __restrict__ xrPrev,
                                            float* __restrict__ xrNext,
                                            const float* __restrict__ d,
                                            const float* __restrict__ inv,
                                            const unsigned int* __restrict__ dpk,
                                            u64* __restrict__ cm,
                                            const u64* __restrict__ rmPrev,
                                            u64* __restrict__ rmNext,
                                            int* __restrict__ selA,
                                            int* __restrict__ selT,
                                            float* __restrict__ selV,
                                            int it) {
    __shared__ u64 red8[8];
    __shared__ uint4 s_hh[4][410];
    __shared__ uint4 s_ll[4][410];
    __shared__ uint4 dl4[16 * 128];
    const int ag = blockIdx.x, b = blockIdx.y, tid = threadIdx.x;
    const int wave = tid >> 6, lane = tid & 63;
    const int cl = lane & 15, q = lane >> 4;
    const int a0 = ag * 16;

    {
        const uint4* gsrc = (const uint4*)(dpk + (a0 << 9));
        #pragma unroll
        for (int s = 0; s < 4; ++s) {
            int i = tid + 512 * s;
            int row = i >> 7, c4 = i & 127;
            dl4[(row << 7) | (c4 ^ (row & 7))] = gsrc[i];
        }
    }

    const u64* rp = rmPrev + b * NA_;
    u64 am = rp[tid];
    #pragma unroll
    for (int o = 32; o > 0; o >>= 1) am = umax64(am, shfl_xor_u64(am, o));
    if (lane == 0) red8[wave] = am;
    __syncthreads();
    u64 win = red8[0];
    #pragma unroll
    for (int w2 = 1; w2 < 8; ++w2) win = umax64(win, red8[w2]);
    const unsigned int enc = (unsigned int)(win >> 32);
    const unsigned int flat = ~(unsigned int)win;
    const int asel = (int)((flat >> 14) & (NA_ - 1));
    const int tsel = (int)(flat & (T_ - 1));
    const float v = decf(enc);
    if (ag == 0 && tid == 0) {
        selA[it * B_ + b] = asel;
        selT[it * B_ + b] = tsel;
        selV[it * B_ + b] = v;
    }
    const int L = min(A_, (T_ - 1) - tsel);
    const float vv = v * inv[asel];

    {
        int t = ag * 512 + tid;
        float xv = xrPrev[b * T_ + t];
        int o = t - tsel;
        if (L > 0 && o >= 0 && o < L) xv = fmaf(-vv, d[asel * A_ + o], xv);
        xrNext[b * T_ + t] = xv;
    }

    if (L > 0) {
        const int tbeg = max(0, tsel - (A_ - 1));
        const int tend = tsel + L;
        const int ab = tbeg & ~63;
        const int ae = (tend + 63) & ~63;
        const int W = ae - ab;
        const int nch = W >> 6;
        const int NS = W + 512;

        unsigned int* hw = (unsigned int*)s_hh;
        unsigned int* lw = (unsigned int*)s_ll;
        for (int e = tid; e < NS + 3; e += 512) {
            int t = ab + e;
            float xv = (t < T_) ? xrPrev[b * T_ + t] : 0.f;
            int o = t - tsel;
            if (o >= 0 && o < L) xv = fmaf(-vv, d[asel * A_ + o], xv);
            unsigned int pw = packhl(xv);
            unsigned int hword = (pw & 0xffffu) * 0x10001u;
            unsigned int lword = (pw >> 16) * 0x10001u;
            #pragma unroll
            for (int s = 0; s < 4; ++s) {
                int i = e - s;
                if (i >= 0 && i < NS) { hw[s * 1640 + i] = hword; lw[s * 1640 + i] = lword; }
            }
        }
        __syncthreads();

        const uint4* Adl = dl4 + (cl << 7);
        const int sw = cl & 7;
        float ivv[4];
        #pragma unroll
        for (int r = 0; r < 4; ++r) ivv[r] = inv[a0 + 4 * q + r];
        const uint4* bhp = &s_hh[cl & 3][(cl >> 2) + q];
        const uint4* blp = &s_ll[cl & 3][(cl >> 2) + q];

        for (int c = wave; c < nch; c += 8) {
            f32x4 acc[4];
            const f32x4 zero = {0.f, 0.f, 0.f, 0.f};
            #pragma unroll
            for (int tt = 0; tt < 4; ++tt) acc[tt] = zero;

            Frag bh[4], bl[4];
            #pragma unroll
            for (int pp = 0; pp < 4; ++pp) {
                bh[pp].u = bhp[16 * c + 4 * pp];
                bl[pp].u = blp[16 * c + 4 * pp];
            }
            for (int j0 = 0; j0 < A_; j0 += 64) {
                #pragma unroll
                for (int u = 0; u < 4; ++u) {
                    const int jj = j0 + 16 * u;
                    Frag Af;
                    Af.u = Adl[(q + (jj >> 2)) ^ sw];
                    #pragma unroll
                    for (int tt = 0; tt < 4; ++tt)
                        acc[tt] = MFMA16(Af.f, bh[(u + tt) & 3].f, acc[tt]);
                    #pragma unroll
                    for (int tt = 0; tt < 4; ++tt)
                        acc[tt] = MFMA16(Af.f, bl[(u + tt) & 3].f, acc[tt]);
                    bh[u].u = bhp[16 * c + (jj >> 2) + 16];
                    bl[u].u = blp[16 * c + (jj >> 2) + 16];
                }
            }
            #pragma unroll
            for (int r = 0; r < 4; ++r) {
                const int atom = a0 + 4 * q + r;
                u64 mm = 0ull;
                #pragma unroll
                for (int tt = 0; tt < 4; ++tt) {
                    int t = ab + 64 * c + 16 * tt + cl;
                    mm = umax64(mm, enc64(acc[tt][r] * ivv[r], (unsigned int)(atom * T_ + t)));
                }
                mm = umax64(mm, shfl_xor_u64(mm, 1));
                mm = umax64(mm, shfl_xor_u64(mm, 2));
                mm = umax64(mm, shfl_xor_u64(mm, 4));
                mm = umax64(mm, shfl_xor_u64(mm, 8));
                if (cl == 0)
                    cm[((size_t)(b * NA_ + atom) << 8) + (ab >> 6) + c] = mm;
            }
        }
        __syncthreads();
    }

    #pragma unroll
    for (int rr = 0; rr < 2; ++rr) {
        const int row = a0 + wave * 2 + rr;
        const u64* p = cm + ((size_t)(b * NA_ + row) << 8);
        u64 m = umax64(umax64(p[lane], p[lane + 64]),
                       umax64(p[lane + 128], p[lane + 192]));
        #pragma unroll
        for (int o = 32; o > 0; o >>= 1) m = umax64(m, shfl_down_u64(m, o));
        if (lane == 0) rmNext[b * NA_ + row] = m;
    }
}

__global__ void s_init(const float* __restrict__ x, float* __restrict__ xr,
                       u64* __restrict__ cand) {
    int i = blockIdx.x * 256 + threadIdx.x;
    if (i < B_ * T_) xr[i] = x[i];
    if (i < B_) cand[i] = 0ull;
}
__global__ __launch_bounds__(256) void s_scan(const float* __restrict__ xr,
                                              const float* __restrict__ d,
                                              const float* __restrict__ inv,
                                              u64* __restrict__ cand) {
    __shared__ float dLs[A_];
    __shared__ u64 redU[256];
    const int aB = blockIdx.x, b = blockIdx.y, tid = threadIdx.x;
    const float iv = inv[aB];
    for (int i = tid; i < A_; i += 256) dLs[i] = d[aB * A_ + i] * iv;
    __syncthreads();
    const float* xb = xr + b * T_;
    u64 best = 0ull;
    for (int t = tid; t < T_; t += 256) {
        float acc = 0.f;
        int lim = min(A_, T_ - t);
        for (int i = 0; i < lim; ++i) acc = fmaf(dLs[i], xb[t + i], acc);
        best = umax64(best, enc64(acc, (unsigned int)(aB * T_ + t)));
    }
    redU[tid] = best;
    __syncthreads();
    for (int s = 128; s > 0; s >>= 1) {
        if (tid < s) redU[tid] = umax64(redU[tid], redU[tid + s]);
        __syncthreads();
    }
    if (tid == 0) atomicMax(&cand[b], redU[0]);
}
__global__ void s_apply(float* __restrict__ xr, const float* __restrict__ d,
                        const float* __restrict__ inv, u64* __restrict__ cand,
                        int* selA, int* selT, float* selV, int it) {
    const int b = blockIdx.x, tid = threadIdx.x;
    u64 win = cand[b];
    unsigned int enc = (unsigned int)(win >> 32);
    unsigned int flat = ~(unsigned int)win;
    int a = (int)((flat >> 14) & (NA_ - 1)), t = (int)(flat & (T_ - 1));
    float v = decf(enc);
    if (tid == 0) { selA[it * B_ + b] = a; selT[it * B_ + b] = t; selV[it * B_ + b] = v; }
    float vvl = v * inv[a];
    int L = min(A_, (T_ - 1) - t);
    for (int o = tid; o < L; o += 256) xr[b * T_ + t + o] -= vvl * d[a * A_ + o];
    if (tid == 0) cand[b] = 0ull;
}

__global__ __launch_bounds__(256) void k_final(const float* __restrict__ x,
                                               const float* __restrict__ d,
                                               const int* __restrict__ selA,
                                               const int* __restrict__ selT,
                                               const float* __restrict__ selV,
                                               const float* __restrict__ inv,
                                               float* __restrict__ out) {
    const int gid = blockIdx.x * 256 + threadIdx.x;
    const int b = gid >> 14;
    const int t = gid & (T_ - 1);
    float r = x[gid];
    float rec = 0.f;
    for (int k = 0; k < NIT_; ++k) {           // sequential: reference fp order
        int a  = selA[k * B_ + b] & (NA_ - 1);
        int ts = selT[k * B_ + b] & (T_ - 1);
        float vvl = selV[k * B_ + b] * inv[a];
        int o = t - ts;
        int L = min(A_, (T_ - 1) - ts);
        if (o >= 0 && o < L) {
            float c = vvl * d[a * A_ + o];
            r -= c;
            rec += c;
        }
    }
    out[gid] = r;
    out[B_ * T_ + gid] = rec;
}

extern "C" void kernel_launch(void* const* d_in, const int* in_sizes, int n_in,
                              void* d_out, int out_size, void* d_ws, size_t ws_size,
                              hipStream_t stream) {
    const float* x = (const float*)d_in[0];
    const float* d = (const float*)d_in[1];
    float* out = (float*)d_out;
    float* ws = (float*)d_ws;
    const size_t wsf = ws_size / sizeof(float);

    float* inv  = ws + OFF_INV;
    int*   selA = (int*)(ws + OFF_SELA);
    int*   selT = (int*)(ws + OFF_SELT);
    float* selV = ws + OFF_SELV;

    if (wsf < (size_t)S_NEED) return;   // hopeless

    const bool persistOK = wsf >= (size_t)PERS_NEED;
    unsigned int* bar = persistOK ? (unsigned int*)(ws + OFF_BAR) : (unsigned int*)0;

    k_inv<<<dim3(NA_), dim3(64), 0, stream>>>(d, inv, bar);

    if (wsf >= (size_t)MAIN_NEED) {
        u64* cm  = (u64*)(ws + OFF_CM);
        u64* rmA = (u64*)(ws + OFF_RMA);
        u64* rmB = (u64*)(ws + OFF_RMB);
        float* xrA = ws + OFF_XRA;
        float* xrB = ws + OFF_XRB;
        unsigned int* dpk = (unsigned int*)(ws + OFF_DPK);

        if (persistOK) {
            u64* rmW = (u64*)(ws + OFF_RMA);    // u64[2][256]
            k_persist<<<dim3(NA_ / 16, B_), dim3(512), 0, stream>>>(x, xrA, xrB, d, inv,
                                                                    rmW, selA, selT, selV,
                                                                    bar, out);
            return;   // out fully written by k_persist
        }

        k_split_d<<<dim3(NA_ * A_ / 256), dim3(256), 0, stream>>>(d, dpk);
        k_conv<<<dim3(T_ / 256, NA_ / 128, B_), dim3(512), 0, stream>>>(x, dpk, inv, cm, xrA);
        k_tables<<<dim3(B_ * NA_ / 4), dim3(256), 0, stream>>>(cm, rmA);
        for (int it = 0; it < NIT_; ++it) {
            const float* xp = (it & 1) ? xrB : xrA;
            float*       xn = (it & 1) ? xrA : xrB;
            const u64*   ro = (it & 1) ? rmB : rmA;
            u64*         rn = (it & 1) ? rmA : rmB;
            k_it<<<dim3(NA_ / 16, B_), dim3(512), 0, stream>>>(xp, xn, d, inv, dpk,
                                                               cm, ro, rn,
                                                               selA, selT, selV, it);
        }
    } else {
        float* xr = ws + OFF_SXR;
        u64* cand = (u64*)(ws + OFF_SCAND);
        s_init<<<dim3((B_ * T_ + 255) / 256), dim3(256), 0, stream>>>(x, xr, cand);
        for (int it = 0; it < NIT_; ++it) {
            s_scan<<<dim3(NA_, B_), dim3(256), 0, stream>>>(xr, d, inv, cand);
            s_apply<<<dim3(B_), dim3(256), 0, stream>>>(xr, d, inv, cand, selA, selT, selV, it);
        }
    }

    k_final<<<dim3(B_ * T_ / 256), dim3(256), 0, stream>>>(x, d, selA, selT, selV, inv, out);
}